// Round 22
// baseline (426.819 us; speedup 1.0000x reference)
//
#include <hip/hip_runtime.h>
#include <hip/hip_bf16.h>
#include <math.h>

// ---- problem constants ----
#define B_SZ     2
#define SEQ      4096
#define DMODEL   1024
#define DSTATE   128
#define HEADDIM  64
#define CHUNK    256
#define DINNER   2048
#define DSSM     2048
#define NHEADS   32
#define CONVDIM  2304       // DSSM + 2*DSTATE
#define DOUTSZ   1024
#define NC       16         // SEQ / CHUNK
#define EPSF     1e-5f

typedef __hip_bfloat16 bf16;
typedef __attribute__((ext_vector_type(8))) short bf16x8;
typedef __attribute__((ext_vector_type(4))) float f32x4;

__device__ __forceinline__ float siluf(float x) { return x / (1.0f + expf(-x)); }

__device__ __forceinline__ float bfu(unsigned short u) {
    union { unsigned int i; float f; } c; c.i = ((unsigned int)u) << 16; return c.f;
}
__device__ __forceinline__ unsigned short f2bf(float f) {
    union { float f; unsigned int u; } c; c.f = f;
    unsigned int u = c.u;
    return (unsigned short)((u + 0x7FFFu + ((u >> 16) & 1u)) >> 16);
}

// async global(16B) -> LDS (wave-uniform base + lane*16; global addr per-lane)
__device__ __forceinline__ void gload16(const void* g, void* l) {
    typedef __attribute__((address_space(1))) const unsigned int GU;
    typedef __attribute__((address_space(3))) unsigned int LU;
    __builtin_amdgcn_global_load_lds((GU*)g, (LU*)l, 16, 0, 0);
}

// ============================================================
// fused fp32 -> bf16 cast over three regions, one launch.
// ============================================================
__global__ __launch_bounds__(256)
void cast3_f32_bf16(const float* __restrict__ s1, unsigned short* __restrict__ d1, int n1,
                    const float* __restrict__ s2, unsigned short* __restrict__ d2, int n2,
                    const float* __restrict__ s3, unsigned short* __restrict__ d3)
{
    int blk = blockIdx.x;
    const float* src; unsigned short* dst;
    if (blk < n1)            { src = s1; dst = d1; }
    else if (blk < n1 + n2)  { src = s2; dst = d2; blk -= n1; }
    else                     { src = s3; dst = d3; blk -= n1 + n2; }
    const long long i = ((long long)blk * 256 + threadIdx.x) * 8;
    float4 a = *(const float4*)(src + i);
    float4 b = *(const float4*)(src + i + 4);
    bf16x8 o;
    o[0] = (short)f2bf(a.x); o[1] = (short)f2bf(a.y);
    o[2] = (short)f2bf(a.z); o[3] = (short)f2bf(a.w);
    o[4] = (short)f2bf(b.x); o[5] = (short)f2bf(b.y);
    o[6] = (short)f2bf(b.z); o[7] = (short)f2bf(b.w);
    *(bf16x8*)(dst + i) = o;
}

// ============================================================
// 8-PHASE 256x256-tile bf16 MFMA NT GEMM (inproj). BK=32, pair of K-tiles
// per iteration, double-buffered pair (LDS 128KB). Per phase: one output
// quadrant (8 MFMA) + 6 ds_reads + 1 gload16 of next pair. vmcnt(4) only
// at phases 3/7 (counted: 4 loads issued after the awaited group).
// ============================================================
template<bool SPLIT, typename TC>
__global__ __launch_bounds__(512)
void gemm8p_256(const short* __restrict__ A, const short* __restrict__ B,
                TC* __restrict__ C0, TC* __restrict__ C1, int M, int N, int K)
{
    const int nwg = gridDim.x * gridDim.y;
    const int orig = blockIdx.y * gridDim.x + blockIdx.x;
    const int q = nwg >> 3, r = nwg & 7;
    const int xcd = orig & 7, rest = orig >> 3;
    const int wgid = (xcd < r ? xcd * (q + 1) : r * (q + 1) + (xcd - r) * q) + rest;
    const int bx = wgid % gridDim.x;
    const int by = wgid / gridDim.x;

    __shared__ short As[2][2][256 * 32];   // [pairbuf][ktile] 16KB each = 64KB
    __shared__ short Bs[2][2][256 * 32];   // 64KB; total 128KB -> 1 block/CU

    const int tid  = threadIdx.x;
    const int lane = tid & 63;
    const int wid  = tid >> 6;
    const int wr = (wid >> 2) * 128;
    const int wc = (wid & 3) * 64;
    const int frow = lane & 15;
    const int fk   = lane >> 4;
    const int swz  = (fk ^ ((frow >> 1) & 3)) * 8;
    const int m0 = by * 256;
    const int n0 = bx * 256;

    // coalesced staging with chunk-swizzle involution (slots tid, 512+tid)
    const int s0 = tid, s1 = 512 + tid;
    const int r0s = s0 >> 2, c0s = (s0 & 3) ^ ((s0 >> 3) & 3);
    const int r1s = s1 >> 2, c1s = (s1 & 3) ^ ((s1 >> 3) & 3);
    const short* Ag0 = A + (long long)(m0 + r0s) * K + c0s * 8;
    const short* Ag1 = A + (long long)(m0 + r1s) * K + c1s * 8;
    const short* Bg0 = B + (long long)(n0 + r0s) * K + c0s * 8;
    const short* Bg1 = B + (long long)(n0 + r1s) * K + c1s * 8;

    const int dg0 = (wid * 64) * 8;          // wave-uniform LDS dest (slot group 0)
    const int dg1 = (512 + wid * 64) * 8;    // slot group 1

    f32x4 acc[8][4];
    #pragma unroll
    for (int i = 0; i < 8; ++i)
        #pragma unroll
        for (int j = 0; j < 4; ++j) acc[i][j] = (f32x4)(0.0f);

    const int NTP = K / 64;   // iterations (pairs of 32-wide K-tiles)

    // prologue: stage pair 0 into buf 0 (8 loads); wait its K-tile 0 (4 newest outstanding ok)
    gload16(Ag0,      &As[0][0][dg0]); gload16(Ag1,      &As[0][0][dg1]);
    gload16(Bg0,      &Bs[0][0][dg0]); gload16(Bg1,      &Bs[0][0][dg1]);
    gload16(Ag0 + 32, &As[0][1][dg0]); gload16(Ag1 + 32, &As[0][1][dg1]);
    gload16(Bg0 + 32, &Bs[0][1][dg0]); gload16(Bg1 + 32, &Bs[0][1][dg1]);
    asm volatile("s_waitcnt vmcnt(4)" ::: "memory");
    __builtin_amdgcn_sched_barrier(0);
    __builtin_amdgcn_s_barrier();

    for (int p = 0; p < NTP; ++p) {
        const int pb = p & 1, qb = pb ^ 1;
        const bool pref = (p + 1 < NTP);
        const int kn = (p + 1) * 64;
        #pragma unroll
        for (int ph = 0; ph < 8; ++ph) {
            const int kt = ph >> 2;
            const int qm = (ph >> 1) & 1, qn = ph & 1;
            const short* Asc = As[pb][kt];
            const short* Bsc = Bs[pb][kt];
            bf16x8 a[4], b[2];
            #pragma unroll
            for (int fm = 0; fm < 4; ++fm)
                a[fm] = *(const bf16x8*)&Asc[(wr + qm * 64 + fm * 16 + frow) * 32 + swz];
            #pragma unroll
            for (int fn = 0; fn < 2; ++fn)
                b[fn] = *(const bf16x8*)&Bsc[(wc + qn * 32 + fn * 16 + frow) * 32 + swz];
            if (pref) {   // stage exactly one next-pair load this phase
                if      (ph == 0) gload16(Ag0 + kn,      &As[qb][0][dg0]);
                else if (ph == 1) gload16(Ag1 + kn,      &As[qb][0][dg1]);
                else if (ph == 2) gload16(Bg0 + kn,      &Bs[qb][0][dg0]);
                else if (ph == 3) gload16(Bg1 + kn,      &Bs[qb][0][dg1]);
                else if (ph == 4) gload16(Ag0 + kn + 32, &As[qb][1][dg0]);
                else if (ph == 5) gload16(Ag1 + kn + 32, &As[qb][1][dg1]);
                else if (ph == 6) gload16(Bg0 + kn + 32, &Bs[qb][1][dg0]);
                else              gload16(Bg1 + kn + 32, &Bs[qb][1][dg1]);
            }
            __builtin_amdgcn_s_barrier();
            __builtin_amdgcn_s_setprio(1);
            #pragma unroll
            for (int fm = 0; fm < 4; ++fm)
                #pragma unroll
                for (int fn = 0; fn < 2; ++fn)
                    acc[qm * 4 + fm][qn * 2 + fn] = __builtin_amdgcn_mfma_f32_16x16x32_bf16(
                        a[fm], b[fn], acc[qm * 4 + fm][qn * 2 + fn], 0, 0, 0);
            __builtin_amdgcn_s_setprio(0);
            if (ph == 3) {
                // current pair K-tile1 must be visible for phases 4-7
                if (pref) asm volatile("s_waitcnt vmcnt(4)" ::: "memory");
                else      asm volatile("s_waitcnt vmcnt(0)" ::: "memory");
                __builtin_amdgcn_sched_barrier(0);
            } else if (ph == 7) {
                // next pair K-tile0 must be visible for next iteration
                if (pref) asm volatile("s_waitcnt vmcnt(4)" ::: "memory");
                __builtin_amdgcn_sched_barrier(0);
            }
            __builtin_amdgcn_s_barrier();
        }
    }

    const int crow = (lane >> 4) * 4;
    const int ccol = lane & 15;
    #pragma unroll
    for (int fm = 0; fm < 8; ++fm) {
        #pragma unroll
        for (int j = 0; j < 4; ++j) {
            long long row = m0 + wr + fm * 16 + crow + j;
            #pragma unroll
            for (int fn = 0; fn < 4; ++fn) {
                int col = n0 + wc + fn * 16 + ccol;
                float v = acc[fm][fn][j];
                if constexpr (SPLIT) {
                    if (col < DSSM)
                        C0[row * DSSM + col] = (TC)f2bf(v);
                    else
                        C1[row * CONVDIM + (col - DSSM)] = (TC)f2bf(v);
                } else {
                    if constexpr (sizeof(TC) == 2) C0[row * N + col] = (TC)f2bf(v);
                    else                           C0[row * N + col] = v;
                }
            }
        }
    }
}

// ============================================================
// 128x128 8-wave pipelined MFMA NT GEMM (Smat batched + out GEMM),
// coalesced staging + XOR swizzle, 3-buf counted-vmcnt pipeline.
// ============================================================
#define G8_DECLS()                                                                \
    __shared__ short As0[128 * 32];                                               \
    __shared__ short As1[128 * 32];                                               \
    __shared__ short As2[128 * 32];                                               \
    __shared__ short Bs0[128 * 32];                                               \
    __shared__ short Bs1[128 * 32];                                               \
    __shared__ short Bs2[128 * 32];                                               \
    const int tid  = threadIdx.x;                                                 \
    const int lane = tid & 63;                                                    \
    const int wid  = tid >> 6;                                                    \
    const int wr = (wid >> 2) * 64;                                               \
    const int wc = (wid & 3) * 32;                                                \
    const int srow = tid >> 2;                                                    \
    const int schk = (tid & 3) ^ ((tid >> 3) & 3);                                \
    short* AsW0 = &As0[(wid * 64) * 8];                                           \
    short* AsW1 = &As1[(wid * 64) * 8];                                           \
    short* AsW2 = &As2[(wid * 64) * 8];                                           \
    short* BsW0 = &Bs0[(wid * 64) * 8];                                           \
    short* BsW1 = &Bs1[(wid * 64) * 8];                                           \
    short* BsW2 = &Bs2[(wid * 64) * 8];                                           \
    const int frow = lane & 15;                                                   \
    const int fk   = lane >> 4;                                                   \
    const int swz  = (fk ^ ((frow >> 1) & 3)) * 8;

#define G8_PIPE(K_)                                                               \
    {                                                                             \
        const int NT = (K_) / 32;                                                 \
        gload16(Ag + 0 * 32, AsW0); gload16(Bg + 0 * 32, BsW0);                   \
        gload16(Ag + 1 * 32, AsW1); gload16(Bg + 1 * 32, BsW1);                   \
        gload16(Ag + 2 * 32, AsW2); gload16(Bg + 2 * 32, BsW2);                   \
        asm volatile("s_waitcnt vmcnt(4)" ::: "memory");                          \
        __builtin_amdgcn_sched_barrier(0);                                        \
        __builtin_amdgcn_s_barrier();                                             \
        for (int t = 0; t < NT; ++t) {                                            \
            const int cur = t % 3;                                                \
            const short* Asc = cur == 0 ? As0 : (cur == 1 ? As1 : As2);           \
            const short* Bsc = cur == 0 ? Bs0 : (cur == 1 ? Bs1 : Bs2);           \
            bf16x8 a[4], b[2];                                                    \
            _Pragma("unroll")                                                     \
            for (int fm = 0; fm < 4; ++fm)                                        \
                a[fm] = *(const bf16x8*)&Asc[(wr + fm * 16 + frow) * 32 + swz];   \
            _Pragma("unroll")                                                     \
            for (int fn = 0; fn < 2; ++fn)                                        \
                b[fn] = *(const bf16x8*)&Bsc[(wc + fn * 16 + frow) * 32 + swz];   \
            _Pragma("unroll")                                                     \
            for (int fm = 0; fm < 4; ++fm)                                        \
                _Pragma("unroll")                                                 \
                for (int fn = 0; fn < 2; ++fn)                                    \
                    acc[fm][fn] = __builtin_amdgcn_mfma_f32_16x16x32_bf16(        \
                        a[fm], b[fn], acc[fm][fn], 0, 0, 0);                      \
            __builtin_amdgcn_s_barrier();                                         \
            if (t + 3 < NT) {                                                     \
                short* stA = cur == 0 ? AsW0 : (cur == 1 ? AsW1 : AsW2);          \
                short* stB = cur == 0 ? BsW0 : (cur == 1 ? BsW1 : BsW2);          \
                gload16(Ag + (t + 3) * 32, stA);                                  \
                gload16(Bg + (t + 3) * 32, stB);                                  \
                asm volatile("s_waitcnt vmcnt(4)" ::: "memory");                  \
            } else if (t + 2 < NT) {                                              \
                asm volatile("s_waitcnt vmcnt(2)" ::: "memory");                  \
            } else if (t + 1 < NT) {                                              \
                asm volatile("s_waitcnt vmcnt(0)" ::: "memory");                  \
            }                                                                     \
            __builtin_amdgcn_sched_barrier(0);                                    \
            __builtin_amdgcn_s_barrier();                                         \
        }                                                                         \
    }

template<typename TC>
__global__ __launch_bounds__(512)
void gemm_mfma_nt(const short* __restrict__ A, const short* __restrict__ B,
                  TC* __restrict__ C, int M, int N, int K,
                  long long sA, long long sB, long long sC)
{
    A += (long long)blockIdx.z * sA;
    B += (long long)blockIdx.z * sB;
    C += (long long)blockIdx.z * sC;

    const int nwg = gridDim.x * gridDim.y;
    const int orig = blockIdx.y * gridDim.x + blockIdx.x;
    const int q = nwg >> 3, r = nwg & 7;
    const int xcd = orig & 7, rest = orig >> 3;
    const int wgid = (xcd < r ? xcd * (q + 1) : r * (q + 1) + (xcd - r) * q) + rest;
    const int bx = wgid % gridDim.x;
    const int by = wgid / gridDim.x;

    G8_DECLS()

    const int m0 = by * 128;
    const int n0 = bx * 128;
    const short* Ag = A + (long long)(m0 + srow) * K + schk * 8;
    const short* Bg = B + (long long)(n0 + srow) * K + schk * 8;

    f32x4 acc[4][2];
    #pragma unroll
    for (int i = 0; i < 4; ++i) { acc[i][0] = (f32x4)(0.f); acc[i][1] = (f32x4)(0.f); }

    G8_PIPE(K)

    const int crow = (lane >> 4) * 4;
    const int ccol = lane & 15;
    #pragma unroll
    for (int fm = 0; fm < 4; ++fm) {
        #pragma unroll
        for (int j = 0; j < 4; ++j) {
            long long row = m0 + wr + fm * 16 + crow + j;
            TC* cp = C + row * N + n0 + wc + ccol;
            #pragma unroll
            for (int fn = 0; fn < 2; ++fn) {
                float v = acc[fm][fn][j];
                if constexpr (sizeof(TC) == 2) cp[fn * 16] = (TC)f2bf(v);
                else                           cp[fn * 16] = v;
            }
        }
    }
}

// ============================================================
// dt column GEMM (fp32): dtraw[m][h] = dot(inp[m], Wdt[h])
// ============================================================
__global__ __launch_bounds__(256)
void dt_gemm_tiled(const float* __restrict__ inp, const float* __restrict__ Wdt,
                   float* __restrict__ dtraw)
{
    const int tid  = threadIdx.x;
    const int row0 = blockIdx.x * 32;
    const int hh   = (tid & 15) * 2;
    const int rr   = (tid >> 4) * 2;

    __shared__ float Wl[32][130];
    __shared__ float Il[32][130];

    float a00 = 0.f, a01 = 0.f, a10 = 0.f, a11 = 0.f;

    for (int k0 = 0; k0 < DMODEL; k0 += 128) {
        #pragma unroll
        for (int it = 0; it < 16; ++it) {
            int idx = it * 256 + tid;
            int r = idx >> 7, c = idx & 127;
            Wl[r][c] = Wdt[(long long)r * DMODEL + k0 + c];
            Il[r][c] = inp[(long long)(row0 + r) * DMODEL + k0 + c];
        }
        __syncthreads();
        #pragma unroll
        for (int kk = 0; kk < 128; kk += 4) {
            float4 w0 = *(const float4*)&Wl[hh][kk];
            float4 w1 = *(const float4*)&Wl[hh + 1][kk];
            float4 i0 = *(const float4*)&Il[rr][kk];
            float4 i1 = *(const float4*)&Il[rr + 1][kk];
            a00 += i0.x * w0.x + i0.y * w0.y + i0.z * w0.z + i0.w * w0.w;
            a01 += i0.x * w1.x + i0.y * w1.y + i0.z * w1.z + i0.w * w1.w;
            a10 += i1.x * w0.x + i1.y * w0.y + i1.z * w0.z + i1.w * w0.w;
            a11 += i1.x * w1.x + i1.y * w1.y + i1.z * w1.z + i1.w * w1.w;
        }
        __syncthreads();
    }
    dtraw[(long long)(row0 + rr) * NHEADS + hh]         = a00;
    dtraw[(long long)(row0 + rr) * NHEADS + hh + 1]     = a01;
    dtraw[(long long)(row0 + rr + 1) * NHEADS + hh]     = a10;
    dtraw[(long long)(row0 + rr + 1) * NHEADS + hh + 1] = a11;
}

// ============================================================
// Depthwise causal conv (width 4) + bias + SiLU; vectorized bf16x8.
// ============================================================
__global__ __launch_bounds__(256)
void conv_silu_v2(const unsigned short* __restrict__ xbc, const float* __restrict__ cw,
                  const float* __restrict__ cb,
                  unsigned short* __restrict__ xconv, unsigned short* __restrict__ Bc,
                  unsigned short* __restrict__ Cc)
{
    const int tid = threadIdx.x;
    const int c8  = (blockIdx.x * 32 + (tid & 31)) * 8;
    const int lf  = blockIdx.y * 8 + (tid >> 5);
    const int b   = lf >> 12;
    const int l   = lf & (SEQ - 1);

    float4 w[8];
    #pragma unroll
    for (int j = 0; j < 8; ++j) w[j] = *(const float4*)(cw + (c8 + j) * 4);

    float acc[8];
    {
        float4 b0 = *(const float4*)(cb + c8);
        float4 b1 = *(const float4*)(cb + c8 + 4);
        acc[0] = b0.x; acc[1] = b0.y; acc[2] = b0.z; acc[3] = b0.w;
        acc[4] = b1.x; acc[5] = b1.y; acc[6] = b1.z; acc[7] = b1.w;
    }
    #pragma unroll
    for (int k = 0; k < 4; ++k) {
        int ls = l - 3 + k;
        if (ls < 0) continue;
        const unsigned short* src = xbc + ((long long)(b * SEQ + ls)) * CONVDIM + c8;
        ushort4 v0 = *(const ushort4*)src;
        ushort4 v1 = *(const ushort4*)(src + 4);
        unsigned short tv[8] = {v0.x, v0.y, v0.z, v0.w, v1.x, v1.y, v1.z, v1.w};
        #pragma unroll
        for (int j = 0; j < 8; ++j) {
            const float* wj = (const float*)&w[j];
            acc[j] += bfu(tv[j]) * wj[k];
        }
    }
    bf16x8 o;
    #pragma unroll
    for (int j = 0; j < 8; ++j) {
        float v = acc[j];
        v = v / (1.0f + __expf(-v));
        o[j] = (short)f2bf(v);
    }
    if (c8 < DSSM)
        *(bf16x8*)(xconv + (long long)lf * DSSM + c8) = o;
    else if (c8 < DSSM + DSTATE)
        *(bf16x8*)(Bc + (long long)lf * DSTATE + (c8 - DSSM)) = o;
    else
        *(bf16x8*)(Cc + (long long)lf * DSTATE + (c8 - DSSM - DSTATE)) = o;
}

// ============================================================
// cumsum of dA per (b,h,chunk), with fused softplus (writes dtp too)
// ============================================================
__global__ __launch_bounds__(256)
void cumsum_da(const float* __restrict__ dtraw, const float* __restrict__ dt_bias,
               const float* __restrict__ A_log, float* __restrict__ dtp,
               float* __restrict__ cs)
{
    const int bid = blockIdx.x;
    const int z = bid % NC;
    const int h = (bid / NC) % NHEADS;
    const int b = bid / (NC * NHEADS);
    const int t = threadIdx.x;

    const float Ah = -expf(A_log[h]);
    const int lg = z * CHUNK + t;
    const long long fi = ((long long)(b * SEQ) + lg) * NHEADS + h;
    float x = dtraw[fi] + dt_bias[h];
    float sp = (x > 20.f) ? x : log1pf(expf(x));
    dtp[fi] = sp;
    float v = sp * Ah;

    __shared__ float s[CHUNK];
    s[t] = v;
    __syncthreads();
    for (int off = 1; off < CHUNK; off <<= 1) {
        float add = (t >= off) ? s[t - off] : 0.f;
        __syncthreads();
        s[t] += add;
        __syncthreads();
    }
    cs[((long long)(b * NHEADS) + h) * SEQ + lg] = s[t];
}

// ============================================================
// xdT[b,h,p,s] = xconv[s, h*64+p] * dtp[s,h]   (transposed)
// ============================================================
__global__ __launch_bounds__(256)
void xdt_prep(const unsigned short* __restrict__ xconv, const float* __restrict__ dtp,
              unsigned short* __restrict__ xdT)
{
    const int st = blockIdx.x;
    const int h  = blockIdx.y;
    const int b  = blockIdx.z;
    const int tid = threadIdx.x;
    const int s0t = st * 128;

    __shared__ short T[128][66];
    __shared__ float scale[128];

    if (tid < 128) {
        int sg = s0t + tid;
        scale[tid] = dtp[((long long)(b * SEQ) + sg) * NHEADS + h];
    }
    __syncthreads();

    #pragma unroll
    for (int it = 0; it < 4; ++it) {
        int c = it * 256 + tid;
        int row = c >> 3, pc = c & 7;
        const unsigned short* src =
            xconv + ((long long)(b * SEQ) + s0t + row) * DSSM + h * 64 + pc * 8;
        ushort4 v0 = *(const ushort4*)src;
        ushort4 v1 = *(const ushort4*)(src + 4);
        float sc = scale[row];
        unsigned short tv[8] = {v0.x, v0.y, v0.z, v0.w, v1.x, v1.y, v1.z, v1.w};
        #pragma unroll
        for (int j = 0; j < 8; ++j) T[row][pc * 8 + j] = (short)f2bf(bfu(tv[j]) * sc);
    }
    __syncthreads();

    #pragma unroll
    for (int it = 0; it < 4; ++it) {
        int c = it * 256 + tid;
        int p = c >> 4, scc = c & 15;
        bf16x8 o;
        #pragma unroll
        for (int j = 0; j < 8; ++j) o[j] = T[scc * 8 + j][p];
        *(bf16x8*)(xdT + (((long long)(b * NHEADS) + h) * 64 + p) * SEQ + s0t + scc * 8) = o;
    }
}

// ============================================================
// BT[b][n][s] = Bc[b*SEQ+s][n]  (bf16 transpose)
// ============================================================
__global__ __launch_bounds__(256)
void bt_prep(const unsigned short* __restrict__ Bc, unsigned short* __restrict__ BT)
{
    const int st = blockIdx.x;
    const int b  = blockIdx.y;
    const int tid = threadIdx.x;
    const int s0t = st * 128;

    __shared__ short T[128][130];

    #pragma unroll
    for (int it = 0; it < 8; ++it) {
        int c = it * 256 + tid;
        int row = c >> 4, nc = c & 15;
        const unsigned short* src = Bc + ((long long)(b * SEQ) + s0t + row) * DSTATE + nc * 8;
        ushort4 v0 = *(const ushort4*)src;
        ushort4 v1 = *(const ushort4*)(src + 4);
        T[row][nc * 8 + 0] = v0.x; T[row][nc * 8 + 1] = v0.y;
        T[row][nc * 8 + 2] = v0.z; T[row][nc * 8 + 3] = v0.w;
        T[row][nc * 8 + 4] = v1.x; T[row][nc * 8 + 5] = v1.y;
        T[row][nc * 8 + 6] = v1.z; T[row][nc * 8 + 7] = v1.w;
    }
    __syncthreads();

    #pragma unroll
    for (int it = 0; it < 8; ++it) {
        int c = it * 256 + tid;
        int n = c >> 4, scc = c & 15;
        bf16x8 o;
        #pragma unroll
        for (int j = 0; j < 8; ++j) o[j] = T[scc * 8 + j][n];
        *(bf16x8*)(BT + ((long long)b * DSTATE + n) * SEQ + s0t + scc * 8) = o;
    }
}

// ============================================================
// chunk_states (MFMA): states[p,n] = sum_l xdT[p,l] * B[l,n] * dec[l]
// Xs staging coalesced + swizzled (involution).
// ============================================================
__global__ __launch_bounds__(256)
void chunk_states_mfma(const unsigned short* __restrict__ BT,
                       const unsigned short* __restrict__ xdT,
                       const float* __restrict__ cs,
                       unsigned short* __restrict__ statesbf)
{
    const int h  = blockIdx.x & 31;
    const int bz = blockIdx.x >> 5;
    const int z  = bz & (NC - 1);
    const int b  = bz >> 4;
    const int tid = threadIdx.x;
    const int lane = tid & 63;
    const int wid = tid >> 6;
    const int frow = lane & 15;
    const int fk = lane >> 4;
    const int wn = wid * 32;
    const int swz = (fk ^ ((frow >> 1) & 3)) * 8;

    __shared__ __attribute__((aligned(16))) short Xs[64 * 32];       // xdT tile [64p][32l]
    __shared__ __attribute__((aligned(16))) short Bs2[4 * 128 * 8];  // B*dec segs
    __shared__ float dec[CHUNK];

    const long long csbase = ((long long)(b * NHEADS) + h) * SEQ + (long long)z * CHUNK;
    {
        float clast = cs[csbase + CHUNK - 1];
        dec[tid] = __expf(clast - cs[csbase + tid]);   // exponent <= 0, safe
    }
    __syncthreads();

    f32x4 acc[4][2];
    #pragma unroll
    for (int i = 0; i < 4; ++i) { acc[i][0] = (f32x4)(0.f); acc[i][1] = (f32x4)(0.f); }

    const unsigned short* xdbase = xdT + (((long long)(b * NHEADS) + h) * 64) * SEQ + (long long)z * CHUNK;
    const unsigned short* btbase = BT + (long long)b * DSTATE * SEQ + (long long)z * CHUNK;

    const int sp_ = tid >> 2;
    const int sc_ = (tid & 3) ^ ((tid >> 3) & 3);
    short* XsW = &Xs[(wid * 64) * 8];

    for (int l0 = 0; l0 < CHUNK; l0 += 32) {
        gload16(xdbase + (long long)sp_ * SEQ + l0 + sc_ * 8, XsW);
        #pragma unroll
        for (int r = 0; r < 2; ++r) {
            int sidx = r * 256 + tid;
            int n = sidx & 127, lseg = sidx >> 7;
            const unsigned short* sp = btbase + (long long)n * SEQ + l0 + lseg * 8;
            ushort4 v0 = *(const ushort4*)sp;
            ushort4 v1 = *(const ushort4*)(sp + 4);
            unsigned short tv[8] = {v0.x, v0.y, v0.z, v0.w, v1.x, v1.y, v1.z, v1.w};
            bf16x8 o;
            #pragma unroll
            for (int j = 0; j < 8; ++j)
                o[j] = (short)f2bf(bfu(tv[j]) * dec[l0 + lseg * 8 + j]);
            *(bf16x8*)&Bs2[sidx * 8] = o;
        }
        __syncthreads();
        bf16x8 a[4], bb[2];
        #pragma unroll
        for (int fm = 0; fm < 4; ++fm)
            a[fm] = *(const bf16x8*)&Xs[(fm * 16 + frow) * 32 + swz];
        #pragma unroll
        for (int fn = 0; fn < 2; ++fn)
            bb[fn] = *(const bf16x8*)&Bs2[(fk * 128 + wn + fn * 16 + frow) * 8];
        #pragma unroll
        for (int fm = 0; fm < 4; ++fm)
            #pragma unroll
            for (int fn = 0; fn < 2; ++fn)
                acc[fm][fn] = __builtin_amdgcn_mfma_f32_16x16x32_bf16(
                    a[fm], bb[fn], acc[fm][fn], 0, 0, 0);
        __syncthreads();
    }

    unsigned short* st = statesbf + ((long long)(bz * NHEADS + h)) * HEADDIM * DSTATE;
    const int crow = (lane >> 4) * 4;
    const int ccol = lane & 15;
    #pragma unroll
    for (int fm = 0; fm < 4; ++fm)
        #pragma unroll
        for (int j = 0; j < 4; ++j) {
            int p = fm * 16 + crow + j;
            #pragma unroll
            for (int fn = 0; fn < 2; ++fn)
                st[p * DSTATE + wn + fn * 16 + ccol] = f2bf(acc[fm][fn][j]);
        }
}

// ============================================================
// Inter-chunk scan, bf16 in place: states[z] <- prev[z] (carry in fp32)
// ============================================================
__global__ __launch_bounds__(256)
void chunk_scan(unsigned short* __restrict__ states, const float* __restrict__ cs)
{
    int f = blockIdx.x * 256 + threadIdx.x;
    int n = f & 127;
    int p = (f >> 7) & 63;
    int h = (f >> 13) & 31;
    int b = f >> 18;

    float carry = 0.f;
    for (int z = 0; z < NC; ++z) {
        long long idx = ((((long long)(b * NC + z) * NHEADS) + h) * HEADDIM + p) * DSTATE + n;
        float st = bfu(states[idx]);
        states[idx] = f2bf(carry);
        float cd = expf(cs[((long long)(b * NHEADS) + h) * SEQ + z * CHUNK + CHUNK - 1]);
        carry = carry * cd + st;
    }
}

// ============================================================
// Fused Y, row-split: grid (1024, 2); block handles 128 rows of one (b,z,h).
// Xs staging coalesced + swizzled (involution).
// ============================================================
__global__ __launch_bounds__(256)
void y_fused(const unsigned short* __restrict__ Smat, const unsigned short* __restrict__ Cc,
             const unsigned short* __restrict__ xdT, const unsigned short* __restrict__ prevbf,
             const float* __restrict__ cs, const float* __restrict__ Dv,
             const unsigned short* __restrict__ xconv, unsigned short* __restrict__ y)
{
    const int h  = blockIdx.x & 31;
    const int bz = blockIdx.x >> 5;
    const int z  = bz & (NC - 1);
    const int b  = bz >> 4;
    const int r0 = blockIdx.y * 128;
    const int tid = threadIdx.x;
    const int lane = tid & 63;
    const int wid = tid >> 6;
    const int frow = lane & 15;
    const int fk = lane >> 4;
    const int wr = wid * 32;
    const int swz = (fk ^ ((frow >> 1) & 3)) * 8;

    __shared__ __attribute__((aligned(16))) short Ms[4 * 128 * 8];
    __shared__ __attribute__((aligned(16))) short Xs[64 * 32];
    __shared__ float css[CHUNK];

    const long long csbase = ((long long)(b * NHEADS) + h) * SEQ + (long long)z * CHUNK;
    const long long rowbase = (long long)b * SEQ + (long long)z * CHUNK;

    css[tid] = cs[csbase + tid];
    __syncthreads();

    const int lrow = tid & 127;
    const int grow = r0 + lrow;
    const int g0   = (tid >> 7) * 2;
    const float cl = css[grow];

    const int sp_ = tid >> 2;
    const int sc_ = (tid & 3) ^ ((tid >> 3) & 3);
    short* XsW = &Xs[(wid * 64) * 8];

    f32x4 acc[2][4];
    #pragma unroll
    for (int i = 0; i < 2; ++i)
        #pragma unroll
        for (int j = 0; j < 4; ++j) acc[i][j] = (f32x4)(0.0f);

    const unsigned short* Srow = Smat + ((long long)bz * CHUNK + grow) * CHUNK;
    const unsigned short* xdbase = xdT + (((long long)(b * NHEADS) + h) * 64) * SEQ + (long long)z * CHUNK;

    // ---- phase 1: masked-S (pairwise decay) @ xdT ----
    for (int s0 = 0; s0 < r0 + 128; s0 += 32) {
        gload16(xdbase + (long long)sp_ * SEQ + s0 + sc_ * 8, XsW);
        #pragma unroll
        for (int gg = 0; gg < 2; ++gg) {
            const int g = g0 + gg;
            bf16x8 o;
            if (s0 + g * 8 <= grow) {
                const unsigned short* sp = Srow + s0 + g * 8;
                ushort4 v0 = *(const ushort4*)sp;
                ushort4 v1 = *(const ushort4*)(sp + 4);
                unsigned short tv[8] = {v0.x, v0.y, v0.z, v0.w, v1.x, v1.y, v1.z, v1.w};
                #pragma unroll
                for (int j = 0; j < 8; ++j) {
                    int sg = s0 + g * 8 + j;
                    float m = (sg <= grow) ? bfu(tv[j]) * __expf(cl - css[sg]) : 0.f;
                    o[j] = (short)f2bf(m);
                }
            } else {
                #pragma unroll
                for (int j = 0; j < 8; ++j) o[j] = 0;
            }
            *(bf16x8*)&Ms[(g * 128 + lrow) * 8] = o;
        }
        __syncthreads();
        if (s0 <= r0 + wr + 31) {
            __builtin_amdgcn_s_setprio(1);
            bf16x8 a[2], bb[4];
            #pragma unroll
            for (int fm = 0; fm < 2; ++fm)
                a[fm] = *(const bf16x8*)&Ms[(fk * 128 + wr + fm * 16 + frow) * 8];
            #pragma unroll
            for (int fn = 0; fn < 4; ++fn)
                bb[fn] = *(const bf16x8*)&Xs[(fn * 16 + frow) * 32 + swz];
            #pragma unroll
            for (int fm = 0; fm < 2; ++fm)
                #pragma unroll
                for (int fn = 0; fn < 4; ++fn)
                    acc[fm][fn] = __builtin_amdgcn_mfma_f32_16x16x32_bf16(
                        a[fm], bb[fn], acc[fm][fn], 0, 0, 0);
            __builtin_amdgcn_s_setprio(0);
        }
        __syncthreads();
    }

    // ---- phase 2: (C*exp(cs_l)) @ prev ----
    const float el = __expf(cl);
    const unsigned short* Crow = Cc + (rowbase + grow) * DSTATE;
    const unsigned short* pvb = prevbf + (long long)(bz * NHEADS + h) * HEADDIM * DSTATE;
    for (int n0 = 0; n0 < DSTATE; n0 += 32) {
        gload16(pvb + (long long)sp_ * DSTATE + n0 + sc_ * 8, XsW);
        #pragma unroll
        for (int gg = 0; gg < 2; ++gg) {
            const int g = g0 + gg;
            const unsigned short* sp = Crow + n0 + g * 8;
            ushort4 v0 = *(const ushort4*)sp;
            ushort4 v1 = *(const ushort4*)(sp + 4);
            unsigned short tv[8] = {v0.x, v0.y, v0.z, v0.w, v1.x, v1.y, v1.z, v1.w};
            bf16x8 o;
            #pragma unroll
            for (int j = 0; j < 8; ++j) o[j] = (short)f2bf(bfu(tv[j]) * el);
            *(bf16x8*)&Ms[(g * 128 + lrow) * 8] = o;
        }
        __syncthreads();
        {
            __builtin_amdgcn_s_setprio(1);
            bf16x8 a[2], bb[4];
            #pragma unroll
            for (int fm = 0; fm < 2; ++fm)
                a[fm] = *(const bf16x8*)&Ms[(fk * 128 + wr + fm * 16 + frow) * 8];
            #pragma unroll
            for (int fn = 0; fn < 4; ++fn)
                bb[fn] = *(const bf16x8*)&Xs[(fn * 16 + frow) * 32 + swz];
            #pragma unroll
            for (int fm = 0; fm < 2; ++fm)
                #pragma unroll
                for (int fn = 0; fn < 4; ++fn)
                    acc[fm][fn] = __builtin_amdgcn_mfma_f32_16x16x32_bf16(
                        a[fm], bb[fn], acc[fm][fn], 0, 0, 0);
            __builtin_amdgcn_s_setprio(0);
        }
        __syncthreads();
    }

    // ---- epilogue: + D_h * x ----
    const float Dh = Dv[h];
    const int crow = (lane >> 4) * 4;
    const int ccol = lane & 15;
    #pragma unroll
    for (int fm = 0; fm < 2; ++fm) {
        #pragma unroll
        for (int j = 0; j < 4; ++j) {
            long long row = rowbase + r0 + wr + fm * 16 + crow + j;
            const unsigned short* xr = xconv + row * DSSM + h * 64;
            unsigned short* yr = y + row * DSSM + h * 64;
            #pragma unroll
            for (int fn = 0; fn < 4; ++fn) {
                int p = fn * 16 + ccol;
                yr[p] = f2bf(acc[fm][fn][j] + Dh * bfu(xr[p]));
            }
        }
    }
}

// ============================================================
__global__ __launch_bounds__(256)
void gated_rmsnorm(bf16* __restrict__ y, const bf16* __restrict__ z,
                   const float* __restrict__ nw)
{
    const int row = blockIdx.x;
    const int tid = threadIdx.x;
    bf16* yr = y + (long long)row * DSSM;
    const bf16* zr = z + (long long)row * DSSM;

    float t[8];
    float ss = 0.f;
    const int c0 = tid * 8;
    #pragma unroll
    for (int j = 0; j < 8; ++j) {
        float zv = __bfloat162float(zr[c0 + j]);
        float tv = __bfloat162float(yr[c0 + j]) * siluf(zv);
        t[j] = tv;
        ss += tv * tv;
    }
    #pragma unroll
    for (int off = 32; off > 0; off >>= 1) ss += __shfl_down(ss, off);
    __shared__ float red[4];
    if ((tid & 63) == 0) red[tid >> 6] = ss;
    __syncthreads();
    float tot = red[0] + red[1] + red[2] + red[3];
    float rs = rsqrtf(tot / (float)DSSM + EPSF);
    #pragma unroll
    for (int j = 0; j < 8; ++j)
        yr[c0 + j] = __float2bfloat16(t[j] * rs * nw[c0 + j]);
}

// ============================================================
extern "C" void kernel_launch(void* const* d_in, const int* in_sizes, int n_in,
                              void* d_out, int out_size, void* d_ws, size_t ws_size,
                              hipStream_t stream)
{
    const float* inp     = (const float*)d_in[0];
    const float* W_in    = (const float*)d_in[1];
    const float* conv_w  = (const float*)d_in[2];
    const float* conv_b  = (const float*)d_in[3];
    const float* dt_bias = (const float*)d_in[4];
    const float* A_log   = (const float*)d_in[5];
    const float* Dv      = (const float*)d_in[6];
    const float* norm_w  = (const float*)d_in[7];
    const float* W_out   = (const float*)d_in[8];
    float* out = (float*)d_out;

    char* ws = (char*)d_ws;
    size_t off = 0;
    auto alloc = [&](size_t bytes) -> void* {
        void* p = (void*)(ws + off);
        off = (off + bytes + 255) & ~(size_t)255;
        return p;
    };
    const int MR = B_SZ * SEQ;   // 8192 token rows

    bf16*  zb     = (bf16*) alloc((size_t)MR * DSSM * 2);            // 33.55 MB
    bf16*  xbc    = (bf16*) alloc((size_t)MR * CONVDIM * 2);         // 37.75 MB (dead after conv)
    bf16*  xconv  = (bf16*) alloc((size_t)MR * DSSM * 2);            // 33.55 MB
    bf16*  Bc     = (bf16*) alloc((size_t)MR * DSTATE * 2);          // 2.10 MB
    bf16*  Cc     = (bf16*) alloc((size_t)MR * DSTATE * 2);          // 2.10 MB
    float* dtraw  = (float*)alloc((size_t)MR * NHEADS * 4);          // 1.05 MB
    float* dtp    = (float*)alloc((size_t)MR * NHEADS * 4);          // 1.05 MB
    float* cs     = (float*)alloc((size_t)B_SZ * NHEADS * SEQ * 4);  // 1.05 MB
    unsigned short* statesbf = (unsigned short*)
                    alloc((size_t)B_SZ * NC * NHEADS * HEADDIM * DSTATE * 2);  // 16.78 MB
    unsigned short* Wob = (unsigned short*)alloc((size_t)DOUTSZ * DINNER * 2); // 4.19 MB
    unsigned short* xdT = (unsigned short*)alloc((size_t)B_SZ * NHEADS * 64 * SEQ * 2); // 33.55 MB
    // total ~167 MB

    // aliases (lifetime-disjoint, stream-ordered):
    bf16*  Smat = (bf16*)xbc;                                        // xbc head, after conv
    bf16*  ybuf = (bf16*)((char*)xbc + (size_t)B_SZ * NC * CHUNK * CHUNK * 2);
    unsigned short* BT   = (unsigned short*)ybuf;                    // dead before y_fused writes ybuf
    unsigned short* inpb = (unsigned short*)statesbf;                // dead before chunk_states writes
    unsigned short* Wb   = (unsigned short*)xconv;                   // dead before conv writes xconv

    dim3 blk(256);
    dim3 blk512(512);

    // 0) fused casts to bf16 (one launch): inp, W_in, W_out
    {
        const int n1 = (MR * DMODEL) / 2048;          // 4096
        const int n2 = (4384 * DMODEL) / 2048;        // 2192
        const int n3 = (DOUTSZ * DINNER) / 2048;      // 1024
        cast3_f32_bf16<<<dim3(n1 + n2 + n3), blk, 0, stream>>>(
            inp, inpb, n1, W_in, Wb, n2, W_out, Wob);
    }

    // 1) in_proj: merged z+xBC (N=4352) 8-PHASE 256^2-tile MFMA; dt fp32 tiled
    gemm8p_256<true, unsigned short><<<dim3((DSSM + CONVDIM) / 256, MR / 256), blk512, 0, stream>>>(
        (const short*)inpb, (const short*)Wb,
        (unsigned short*)zb, (unsigned short*)xbc, MR, DSSM + CONVDIM, DMODEL);
    dt_gemm_tiled<<<dim3(MR / 32), blk, 0, stream>>>(
        inp, W_in + (size_t)(DSSM + CONVDIM) * DMODEL, dtraw);

    // 2) conv + silu + split (vectorized; xbc dead afterwards)
    conv_silu_v2<<<dim3(CONVDIM / 256, MR / 8), blk, 0, stream>>>(
        (const unsigned short*)xbc, conv_w, conv_b,
        (unsigned short*)xconv, (unsigned short*)Bc, (unsigned short*)Cc);

    // 3) softplus + cumsum fused
    cumsum_da<<<dim3(B_SZ * NHEADS * NC), blk, 0, stream>>>(dtraw, dt_bias, A_log, dtp, cs);

    // 4) S = Cm @ Bm^T per (b,chunk) -> Smat (128^2 coalesced pipelined, batched)
    gemm_mfma_nt<unsigned short><<<dim3(CHUNK / 128, CHUNK / 128, B_SZ * NC), blk512, 0, stream>>>(
        (const short*)Cc, (const short*)Bc, (unsigned short*)Smat, CHUNK, CHUNK, DSTATE,
        (long long)CHUNK * DSTATE, (long long)CHUNK * DSTATE, (long long)CHUNK * CHUNK);

    // 5) xdT precompute (x * dtp, transposed)
    xdt_prep<<<dim3(SEQ / 128, NHEADS, B_SZ), blk, 0, stream>>>(
        (const unsigned short*)xconv, dtp, xdT);

    // 6) BT precompute (B transposed; aliases ybuf head, dead before step 9)
    bt_prep<<<dim3(SEQ / 128, B_SZ), blk, 0, stream>>>((const unsigned short*)Bc, BT);

    // 7) per-chunk states (MFMA, bf16 out; overwrites inpb region)
    chunk_states_mfma<<<dim3(B_SZ * NC * NHEADS), blk, 0, stream>>>(BT, xdT, cs, statesbf);

    // 8) inter-chunk scan (bf16 in place -> prev)
    chunk_scan<<<dim3(B_SZ * NHEADS * HEADDIM * DSTATE / 256), blk, 0, stream>>>(statesbf, cs);

    // 9) fused Y: Y_diag + Y_off + D*x -> ybuf (row-split, grid x2)
    y_fused<<<dim3(B_SZ * NC * NHEADS, 2), blk, 0, stream>>>(
        (const unsigned short*)Smat, (const unsigned short*)Cc, xdT, statesbf,
        cs, Dv, (const unsigned short*)xconv, (unsigned short*)ybuf);

    // 10) gated RMSNorm (in place on ybuf)
    gated_rmsnorm<<<dim3(MR), blk, 0, stream>>>(ybuf, zb, norm_w);

    // 11) out GEMM: 128^2 coalesced pipelined (512 blocks -> all CUs active)
    gemm_mfma_nt<float><<<dim3(DOUTSZ / 128, MR / 128), blk512, 0, stream>>>(
        (const short*)ybuf, (const short*)Wob, out, MR, DOUTSZ, DINNER, 0, 0, 0);
}

// Round 23
// 397.620 us; speedup vs baseline: 1.0734x; 1.0734x over previous
//
#include <hip/hip_runtime.h>
#include <hip/hip_bf16.h>
#include <math.h>

// ---- problem constants ----
#define B_SZ     2
#define SEQ      4096
#define DMODEL   1024
#define DSTATE   128
#define HEADDIM  64
#define CHUNK    256
#define DINNER   2048
#define DSSM     2048
#define NHEADS   32
#define CONVDIM  2304       // DSSM + 2*DSTATE
#define DOUTSZ   1024
#define NC       16         // SEQ / CHUNK
#define EPSF     1e-5f

typedef __hip_bfloat16 bf16;
typedef __attribute__((ext_vector_type(8))) short bf16x8;
typedef __attribute__((ext_vector_type(4))) float f32x4;

__device__ __forceinline__ float siluf(float x) { return x / (1.0f + expf(-x)); }

__device__ __forceinline__ float bfu(unsigned short u) {
    union { unsigned int i; float f; } c; c.i = ((unsigned int)u) << 16; return c.f;
}
__device__ __forceinline__ unsigned short f2bf(float f) {
    union { float f; unsigned int u; } c; c.f = f;
    unsigned int u = c.u;
    return (unsigned short)((u + 0x7FFFu + ((u >> 16) & 1u)) >> 16);
}

// async global(16B) -> LDS (wave-uniform base + lane*16; global addr per-lane)
__device__ __forceinline__ void gload16(const void* g, void* l) {
    typedef __attribute__((address_space(1))) const unsigned int GU;
    typedef __attribute__((address_space(3))) unsigned int LU;
    __builtin_amdgcn_global_load_lds((GU*)g, (LU*)l, 16, 0, 0);
}

// ============================================================
// fused fp32 -> bf16 cast over three regions, one launch.
// ============================================================
__global__ __launch_bounds__(256)
void cast3_f32_bf16(const float* __restrict__ s1, unsigned short* __restrict__ d1, int n1,
                    const float* __restrict__ s2, unsigned short* __restrict__ d2, int n2,
                    const float* __restrict__ s3, unsigned short* __restrict__ d3)
{
    int blk = blockIdx.x;
    const float* src; unsigned short* dst;
    if (blk < n1)            { src = s1; dst = d1; }
    else if (blk < n1 + n2)  { src = s2; dst = d2; blk -= n1; }
    else                     { src = s3; dst = d3; blk -= n1 + n2; }
    const long long i = ((long long)blk * 256 + threadIdx.x) * 8;
    float4 a = *(const float4*)(src + i);
    float4 b = *(const float4*)(src + i + 4);
    bf16x8 o;
    o[0] = (short)f2bf(a.x); o[1] = (short)f2bf(a.y);
    o[2] = (short)f2bf(a.z); o[3] = (short)f2bf(a.w);
    o[4] = (short)f2bf(b.x); o[5] = (short)f2bf(b.y);
    o[6] = (short)f2bf(b.z); o[7] = (short)f2bf(b.w);
    *(bf16x8*)(dst + i) = o;
}

// ============================================================
// 256x256-tile bf16 MFMA NT GEMM: BK=32, 8 waves, 2-phase dbuf, coalesced
// staging + XOR swizzle involution (rule #21). Proven 113 us @ inproj.
// ============================================================
template<bool SPLIT, typename TC>
__global__ __launch_bounds__(512)
void gemm256_nt(const short* __restrict__ A, const short* __restrict__ B,
                TC* __restrict__ C0, TC* __restrict__ C1, int M, int N, int K)
{
    const int nwg = gridDim.x * gridDim.y;
    const int orig = blockIdx.y * gridDim.x + blockIdx.x;
    const int q = nwg >> 3, r = nwg & 7;
    const int xcd = orig & 7, rest = orig >> 3;
    const int wgid = (xcd < r ? xcd * (q + 1) : r * (q + 1) + (xcd - r) * q) + rest;
    const int bx = wgid % gridDim.x;
    const int by = wgid / gridDim.x;

    __shared__ short As0[256 * 32];
    __shared__ short As1[256 * 32];
    __shared__ short Bs0[256 * 32];
    __shared__ short Bs1[256 * 32];

    const int tid  = threadIdx.x;
    const int lane = tid & 63;
    const int wid  = tid >> 6;
    const int wr = (wid >> 2) * 128;
    const int wc = (wid & 3) * 64;
    const int frow = lane & 15;
    const int fk   = lane >> 4;
    const int m0 = by * 256;
    const int n0 = bx * 256;

    const int s0 = tid, s1 = 512 + tid;
    const int r0s = s0 >> 2, c0s = (s0 & 3) ^ ((s0 >> 3) & 3);
    const int r1s = s1 >> 2, c1s = (s1 & 3) ^ ((s1 >> 3) & 3);
    const short* Ag0 = A + (long long)(m0 + r0s) * K + c0s * 8;
    const short* Ag1 = A + (long long)(m0 + r1s) * K + c1s * 8;
    const short* Bg0 = B + (long long)(n0 + r0s) * K + c0s * 8;
    const short* Bg1 = B + (long long)(n0 + r1s) * K + c1s * 8;

    short* A0w0 = &As0[(wid * 64) * 8];        short* A0w1 = &As0[(512 + wid * 64) * 8];
    short* A1w0 = &As1[(wid * 64) * 8];        short* A1w1 = &As1[(512 + wid * 64) * 8];
    short* B0w0 = &Bs0[(wid * 64) * 8];        short* B0w1 = &Bs0[(512 + wid * 64) * 8];
    short* B1w0 = &Bs1[(wid * 64) * 8];        short* B1w1 = &Bs1[(512 + wid * 64) * 8];

    const int swz = (fk ^ ((frow >> 1) & 3)) * 8;

    f32x4 acc[8][4];
    #pragma unroll
    for (int i = 0; i < 8; ++i)
        #pragma unroll
        for (int j = 0; j < 4; ++j) acc[i][j] = (f32x4)(0.0f);

    const int NT = K / 32;
    gload16(Ag0, A0w0); gload16(Ag1, A0w1);
    gload16(Bg0, B0w0); gload16(Bg1, B0w1);
    __syncthreads();

    int cur = 0;
    for (int t = 0; t < NT; ++t) {
        if (t + 1 < NT) {
            const int k = (t + 1) * 32;
            gload16(Ag0 + k, cur ? A0w0 : A1w0);
            gload16(Ag1 + k, cur ? A0w1 : A1w1);
            gload16(Bg0 + k, cur ? B0w0 : B1w0);
            gload16(Bg1 + k, cur ? B0w1 : B1w1);
        }
        const short* Asc = cur ? As1 : As0;
        const short* Bsc = cur ? Bs1 : Bs0;
        bf16x8 a[8], b[4];
        #pragma unroll
        for (int fm = 0; fm < 8; ++fm)
            a[fm] = *(const bf16x8*)&Asc[(wr + fm * 16 + frow) * 32 + swz];
        #pragma unroll
        for (int fn = 0; fn < 4; ++fn)
            b[fn] = *(const bf16x8*)&Bsc[(wc + fn * 16 + frow) * 32 + swz];
        #pragma unroll
        for (int fm = 0; fm < 8; ++fm)
            #pragma unroll
            for (int fn = 0; fn < 4; ++fn)
                acc[fm][fn] = __builtin_amdgcn_mfma_f32_16x16x32_bf16(
                    a[fm], b[fn], acc[fm][fn], 0, 0, 0);
        __syncthreads();
        cur ^= 1;
    }

    const int crow = (lane >> 4) * 4;
    const int ccol = lane & 15;
    #pragma unroll
    for (int fm = 0; fm < 8; ++fm) {
        #pragma unroll
        for (int j = 0; j < 4; ++j) {
            long long row = m0 + wr + fm * 16 + crow + j;
            #pragma unroll
            for (int fn = 0; fn < 4; ++fn) {
                int col = n0 + wc + fn * 16 + ccol;
                float v = acc[fm][fn][j];
                if constexpr (SPLIT) {
                    if (col < DSSM)
                        C0[row * DSSM + col] = (TC)f2bf(v);
                    else
                        C1[row * CONVDIM + (col - DSSM)] = (TC)f2bf(v);
                } else {
                    if constexpr (sizeof(TC) == 2) C0[row * N + col] = (TC)f2bf(v);
                    else                           C0[row * N + col] = v;
                }
            }
        }
    }
}

// ============================================================
// 128x128 8-wave pipelined MFMA NT GEMM (Smat batched + out GEMM),
// coalesced staging + XOR swizzle, 3-buf counted-vmcnt pipeline.
// ============================================================
#define G8_DECLS()                                                                \
    __shared__ short As0[128 * 32];                                               \
    __shared__ short As1[128 * 32];                                               \
    __shared__ short As2[128 * 32];                                               \
    __shared__ short Bs0[128 * 32];                                               \
    __shared__ short Bs1[128 * 32];                                               \
    __shared__ short Bs2[128 * 32];                                               \
    const int tid  = threadIdx.x;                                                 \
    const int lane = tid & 63;                                                    \
    const int wid  = tid >> 6;                                                    \
    const int wr = (wid >> 2) * 64;                                               \
    const int wc = (wid & 3) * 32;                                                \
    const int srow = tid >> 2;                                                    \
    const int schk = (tid & 3) ^ ((tid >> 3) & 3);                                \
    short* AsW0 = &As0[(wid * 64) * 8];                                           \
    short* AsW1 = &As1[(wid * 64) * 8];                                           \
    short* AsW2 = &As2[(wid * 64) * 8];                                           \
    short* BsW0 = &Bs0[(wid * 64) * 8];                                           \
    short* BsW1 = &Bs1[(wid * 64) * 8];                                           \
    short* BsW2 = &Bs2[(wid * 64) * 8];                                           \
    const int frow = lane & 15;                                                   \
    const int fk   = lane >> 4;                                                   \
    const int swz  = (fk ^ ((frow >> 1) & 3)) * 8;

#define G8_PIPE(K_)                                                               \
    {                                                                             \
        const int NT = (K_) / 32;                                                 \
        gload16(Ag + 0 * 32, AsW0); gload16(Bg + 0 * 32, BsW0);                   \
        gload16(Ag + 1 * 32, AsW1); gload16(Bg + 1 * 32, BsW1);                   \
        gload16(Ag + 2 * 32, AsW2); gload16(Bg + 2 * 32, BsW2);                   \
        asm volatile("s_waitcnt vmcnt(4)" ::: "memory");                          \
        __builtin_amdgcn_sched_barrier(0);                                        \
        __builtin_amdgcn_s_barrier();                                             \
        for (int t = 0; t < NT; ++t) {                                            \
            const int cur = t % 3;                                                \
            const short* Asc = cur == 0 ? As0 : (cur == 1 ? As1 : As2);           \
            const short* Bsc = cur == 0 ? Bs0 : (cur == 1 ? Bs1 : Bs2);           \
            bf16x8 a[4], b[2];                                                    \
            _Pragma("unroll")                                                     \
            for (int fm = 0; fm < 4; ++fm)                                        \
                a[fm] = *(const bf16x8*)&Asc[(wr + fm * 16 + frow) * 32 + swz];   \
            _Pragma("unroll")                                                     \
            for (int fn = 0; fn < 2; ++fn)                                        \
                b[fn] = *(const bf16x8*)&Bsc[(wc + fn * 16 + frow) * 32 + swz];   \
            _Pragma("unroll")                                                     \
            for (int fm = 0; fm < 4; ++fm)                                        \
                _Pragma("unroll")                                                 \
                for (int fn = 0; fn < 2; ++fn)                                    \
                    acc[fm][fn] = __builtin_amdgcn_mfma_f32_16x16x32_bf16(        \
                        a[fm], b[fn], acc[fm][fn], 0, 0, 0);                      \
            __builtin_amdgcn_s_barrier();                                         \
            if (t + 3 < NT) {                                                     \
                short* stA = cur == 0 ? AsW0 : (cur == 1 ? AsW1 : AsW2);          \
                short* stB = cur == 0 ? BsW0 : (cur == 1 ? BsW1 : BsW2);          \
                gload16(Ag + (t + 3) * 32, stA);                                  \
                gload16(Bg + (t + 3) * 32, stB);                                  \
                asm volatile("s_waitcnt vmcnt(4)" ::: "memory");                  \
            } else if (t + 2 < NT) {                                              \
                asm volatile("s_waitcnt vmcnt(2)" ::: "memory");                  \
            } else if (t + 1 < NT) {                                              \
                asm volatile("s_waitcnt vmcnt(0)" ::: "memory");                  \
            }                                                                     \
            __builtin_amdgcn_sched_barrier(0);                                    \
            __builtin_amdgcn_s_barrier();                                         \
        }                                                                         \
    }

template<typename TC>
__global__ __launch_bounds__(512)
void gemm_mfma_nt(const short* __restrict__ A, const short* __restrict__ B,
                  TC* __restrict__ C, int M, int N, int K,
                  long long sA, long long sB, long long sC)
{
    A += (long long)blockIdx.z * sA;
    B += (long long)blockIdx.z * sB;
    C += (long long)blockIdx.z * sC;

    const int nwg = gridDim.x * gridDim.y;
    const int orig = blockIdx.y * gridDim.x + blockIdx.x;
    const int q = nwg >> 3, r = nwg & 7;
    const int xcd = orig & 7, rest = orig >> 3;
    const int wgid = (xcd < r ? xcd * (q + 1) : r * (q + 1) + (xcd - r) * q) + rest;
    const int bx = wgid % gridDim.x;
    const int by = wgid / gridDim.x;

    G8_DECLS()

    const int m0 = by * 128;
    const int n0 = bx * 128;
    const short* Ag = A + (long long)(m0 + srow) * K + schk * 8;
    const short* Bg = B + (long long)(n0 + srow) * K + schk * 8;

    f32x4 acc[4][2];
    #pragma unroll
    for (int i = 0; i < 4; ++i) { acc[i][0] = (f32x4)(0.f); acc[i][1] = (f32x4)(0.f); }

    G8_PIPE(K)

    const int crow = (lane >> 4) * 4;
    const int ccol = lane & 15;
    #pragma unroll
    for (int fm = 0; fm < 4; ++fm) {
        #pragma unroll
        for (int j = 0; j < 4; ++j) {
            long long row = m0 + wr + fm * 16 + crow + j;
            TC* cp = C + row * N + n0 + wc + ccol;
            #pragma unroll
            for (int fn = 0; fn < 2; ++fn) {
                float v = acc[fm][fn][j];
                if constexpr (sizeof(TC) == 2) cp[fn * 16] = (TC)f2bf(v);
                else                           cp[fn * 16] = v;
            }
        }
    }
}

// ============================================================
// dt column GEMM (fp32): dtraw[m][h] = dot(inp[m], Wdt[h])
// ============================================================
__global__ __launch_bounds__(256)
void dt_gemm_tiled(const float* __restrict__ inp, const float* __restrict__ Wdt,
                   float* __restrict__ dtraw)
{
    const int tid  = threadIdx.x;
    const int row0 = blockIdx.x * 32;
    const int hh   = (tid & 15) * 2;
    const int rr   = (tid >> 4) * 2;

    __shared__ float Wl[32][130];
    __shared__ float Il[32][130];

    float a00 = 0.f, a01 = 0.f, a10 = 0.f, a11 = 0.f;

    for (int k0 = 0; k0 < DMODEL; k0 += 128) {
        #pragma unroll
        for (int it = 0; it < 16; ++it) {
            int idx = it * 256 + tid;
            int r = idx >> 7, c = idx & 127;
            Wl[r][c] = Wdt[(long long)r * DMODEL + k0 + c];
            Il[r][c] = inp[(long long)(row0 + r) * DMODEL + k0 + c];
        }
        __syncthreads();
        #pragma unroll
        for (int kk = 0; kk < 128; kk += 4) {
            float4 w0 = *(const float4*)&Wl[hh][kk];
            float4 w1 = *(const float4*)&Wl[hh + 1][kk];
            float4 i0 = *(const float4*)&Il[rr][kk];
            float4 i1 = *(const float4*)&Il[rr + 1][kk];
            a00 += i0.x * w0.x + i0.y * w0.y + i0.z * w0.z + i0.w * w0.w;
            a01 += i0.x * w1.x + i0.y * w1.y + i0.z * w1.z + i0.w * w1.w;
            a10 += i1.x * w0.x + i1.y * w0.y + i1.z * w0.z + i1.w * w0.w;
            a11 += i1.x * w1.x + i1.y * w1.y + i1.z * w1.z + i1.w * w1.w;
        }
        __syncthreads();
    }
    dtraw[(long long)(row0 + rr) * NHEADS + hh]         = a00;
    dtraw[(long long)(row0 + rr) * NHEADS + hh + 1]     = a01;
    dtraw[(long long)(row0 + rr + 1) * NHEADS + hh]     = a10;
    dtraw[(long long)(row0 + rr + 1) * NHEADS + hh + 1] = a11;
}

// ============================================================
// Depthwise causal conv (width 4) + bias + SiLU; vectorized bf16x8.
// ============================================================
__global__ __launch_bounds__(256)
void conv_silu_v2(const unsigned short* __restrict__ xbc, const float* __restrict__ cw,
                  const float* __restrict__ cb,
                  unsigned short* __restrict__ xconv, unsigned short* __restrict__ Bc,
                  unsigned short* __restrict__ Cc)
{
    const int tid = threadIdx.x;
    const int c8  = (blockIdx.x * 32 + (tid & 31)) * 8;
    const int lf  = blockIdx.y * 8 + (tid >> 5);
    const int b   = lf >> 12;
    const int l   = lf & (SEQ - 1);

    float4 w[8];
    #pragma unroll
    for (int j = 0; j < 8; ++j) w[j] = *(const float4*)(cw + (c8 + j) * 4);

    float acc[8];
    {
        float4 b0 = *(const float4*)(cb + c8);
        float4 b1 = *(const float4*)(cb + c8 + 4);
        acc[0] = b0.x; acc[1] = b0.y; acc[2] = b0.z; acc[3] = b0.w;
        acc[4] = b1.x; acc[5] = b1.y; acc[6] = b1.z; acc[7] = b1.w;
    }
    #pragma unroll
    for (int k = 0; k < 4; ++k) {
        int ls = l - 3 + k;
        if (ls < 0) continue;
        const unsigned short* src = xbc + ((long long)(b * SEQ + ls)) * CONVDIM + c8;
        ushort4 v0 = *(const ushort4*)src;
        ushort4 v1 = *(const ushort4*)(src + 4);
        unsigned short tv[8] = {v0.x, v0.y, v0.z, v0.w, v1.x, v1.y, v1.z, v1.w};
        #pragma unroll
        for (int j = 0; j < 8; ++j) {
            const float* wj = (const float*)&w[j];
            acc[j] += bfu(tv[j]) * wj[k];
        }
    }
    bf16x8 o;
    #pragma unroll
    for (int j = 0; j < 8; ++j) {
        float v = acc[j];
        v = v / (1.0f + __expf(-v));
        o[j] = (short)f2bf(v);
    }
    if (c8 < DSSM)
        *(bf16x8*)(xconv + (long long)lf * DSSM + c8) = o;
    else if (c8 < DSSM + DSTATE)
        *(bf16x8*)(Bc + (long long)lf * DSTATE + (c8 - DSSM)) = o;
    else
        *(bf16x8*)(Cc + (long long)lf * DSTATE + (c8 - DSSM - DSTATE)) = o;
}

// ============================================================
// cumsum of dA per (b,h,chunk), with fused softplus (writes dtp too)
// ============================================================
__global__ __launch_bounds__(256)
void cumsum_da(const float* __restrict__ dtraw, const float* __restrict__ dt_bias,
               const float* __restrict__ A_log, float* __restrict__ dtp,
               float* __restrict__ cs)
{
    const int bid = blockIdx.x;
    const int z = bid % NC;
    const int h = (bid / NC) % NHEADS;
    const int b = bid / (NC * NHEADS);
    const int t = threadIdx.x;

    const float Ah = -expf(A_log[h]);
    const int lg = z * CHUNK + t;
    const long long fi = ((long long)(b * SEQ) + lg) * NHEADS + h;
    float x = dtraw[fi] + dt_bias[h];
    float sp = (x > 20.f) ? x : log1pf(expf(x));
    dtp[fi] = sp;
    float v = sp * Ah;

    __shared__ float s[CHUNK];
    s[t] = v;
    __syncthreads();
    for (int off = 1; off < CHUNK; off <<= 1) {
        float add = (t >= off) ? s[t - off] : 0.f;
        __syncthreads();
        s[t] += add;
        __syncthreads();
    }
    cs[((long long)(b * NHEADS) + h) * SEQ + lg] = s[t];
}

// ============================================================
// xdT[b,h,p,s] = xconv[s, h*64+p] * dtp[s,h]   (transposed)
// ============================================================
__global__ __launch_bounds__(256)
void xdt_prep(const unsigned short* __restrict__ xconv, const float* __restrict__ dtp,
              unsigned short* __restrict__ xdT)
{
    const int st = blockIdx.x;
    const int h  = blockIdx.y;
    const int b  = blockIdx.z;
    const int tid = threadIdx.x;
    const int s0t = st * 128;

    __shared__ short T[128][66];
    __shared__ float scale[128];

    if (tid < 128) {
        int sg = s0t + tid;
        scale[tid] = dtp[((long long)(b * SEQ) + sg) * NHEADS + h];
    }
    __syncthreads();

    #pragma unroll
    for (int it = 0; it < 4; ++it) {
        int c = it * 256 + tid;
        int row = c >> 3, pc = c & 7;
        const unsigned short* src =
            xconv + ((long long)(b * SEQ) + s0t + row) * DSSM + h * 64 + pc * 8;
        ushort4 v0 = *(const ushort4*)src;
        ushort4 v1 = *(const ushort4*)(src + 4);
        float sc = scale[row];
        unsigned short tv[8] = {v0.x, v0.y, v0.z, v0.w, v1.x, v1.y, v1.z, v1.w};
        #pragma unroll
        for (int j = 0; j < 8; ++j) T[row][pc * 8 + j] = (short)f2bf(bfu(tv[j]) * sc);
    }
    __syncthreads();

    #pragma unroll
    for (int it = 0; it < 4; ++it) {
        int c = it * 256 + tid;
        int p = c >> 4, scc = c & 15;
        bf16x8 o;
        #pragma unroll
        for (int j = 0; j < 8; ++j) o[j] = T[scc * 8 + j][p];
        *(bf16x8*)(xdT + (((long long)(b * NHEADS) + h) * 64 + p) * SEQ + s0t + scc * 8) = o;
    }
}

// ============================================================
// BT[b][n][s] = Bc[b*SEQ+s][n]  (bf16 transpose)
// ============================================================
__global__ __launch_bounds__(256)
void bt_prep(const unsigned short* __restrict__ Bc, unsigned short* __restrict__ BT)
{
    const int st = blockIdx.x;
    const int b  = blockIdx.y;
    const int tid = threadIdx.x;
    const int s0t = st * 128;

    __shared__ short T[128][130];

    #pragma unroll
    for (int it = 0; it < 8; ++it) {
        int c = it * 256 + tid;
        int row = c >> 4, nc = c & 15;
        const unsigned short* src = Bc + ((long long)(b * SEQ) + s0t + row) * DSTATE + nc * 8;
        ushort4 v0 = *(const ushort4*)src;
        ushort4 v1 = *(const ushort4*)(src + 4);
        T[row][nc * 8 + 0] = v0.x; T[row][nc * 8 + 1] = v0.y;
        T[row][nc * 8 + 2] = v0.z; T[row][nc * 8 + 3] = v0.w;
        T[row][nc * 8 + 4] = v1.x; T[row][nc * 8 + 5] = v1.y;
        T[row][nc * 8 + 6] = v1.z; T[row][nc * 8 + 7] = v1.w;
    }
    __syncthreads();

    #pragma unroll
    for (int it = 0; it < 8; ++it) {
        int c = it * 256 + tid;
        int n = c >> 4, scc = c & 15;
        bf16x8 o;
        #pragma unroll
        for (int j = 0; j < 8; ++j) o[j] = T[scc * 8 + j][n];
        *(bf16x8*)(BT + ((long long)b * DSTATE + n) * SEQ + s0t + scc * 8) = o;
    }
}

// ============================================================
// chunk_states (MFMA): states[p,n] = sum_l xdT[p,l] * B[l,n] * dec[l]
// Xs staging coalesced + swizzled (involution).
// ============================================================
__global__ __launch_bounds__(256)
void chunk_states_mfma(const unsigned short* __restrict__ BT,
                       const unsigned short* __restrict__ xdT,
                       const float* __restrict__ cs,
                       unsigned short* __restrict__ statesbf)
{
    const int h  = blockIdx.x & 31;
    const int bz = blockIdx.x >> 5;
    const int z  = bz & (NC - 1);
    const int b  = bz >> 4;
    const int tid = threadIdx.x;
    const int lane = tid & 63;
    const int wid = tid >> 6;
    const int frow = lane & 15;
    const int fk = lane >> 4;
    const int wn = wid * 32;
    const int swz = (fk ^ ((frow >> 1) & 3)) * 8;

    __shared__ __attribute__((aligned(16))) short Xs[64 * 32];       // xdT tile [64p][32l]
    __shared__ __attribute__((aligned(16))) short Bs2[4 * 128 * 8];  // B*dec segs
    __shared__ float dec[CHUNK];

    const long long csbase = ((long long)(b * NHEADS) + h) * SEQ + (long long)z * CHUNK;
    {
        float clast = cs[csbase + CHUNK - 1];
        dec[tid] = __expf(clast - cs[csbase + tid]);   // exponent <= 0, safe
    }
    __syncthreads();

    f32x4 acc[4][2];
    #pragma unroll
    for (int i = 0; i < 4; ++i) { acc[i][0] = (f32x4)(0.f); acc[i][1] = (f32x4)(0.f); }

    const unsigned short* xdbase = xdT + (((long long)(b * NHEADS) + h) * 64) * SEQ + (long long)z * CHUNK;
    const unsigned short* btbase = BT + (long long)b * DSTATE * SEQ + (long long)z * CHUNK;

    const int sp_ = tid >> 2;
    const int sc_ = (tid & 3) ^ ((tid >> 3) & 3);
    short* XsW = &Xs[(wid * 64) * 8];

    for (int l0 = 0; l0 < CHUNK; l0 += 32) {
        gload16(xdbase + (long long)sp_ * SEQ + l0 + sc_ * 8, XsW);
        #pragma unroll
        for (int r = 0; r < 2; ++r) {
            int sidx = r * 256 + tid;
            int n = sidx & 127, lseg = sidx >> 7;
            const unsigned short* sp = btbase + (long long)n * SEQ + l0 + lseg * 8;
            ushort4 v0 = *(const ushort4*)sp;
            ushort4 v1 = *(const ushort4*)(sp + 4);
            unsigned short tv[8] = {v0.x, v0.y, v0.z, v0.w, v1.x, v1.y, v1.z, v1.w};
            bf16x8 o;
            #pragma unroll
            for (int j = 0; j < 8; ++j)
                o[j] = (short)f2bf(bfu(tv[j]) * dec[l0 + lseg * 8 + j]);
            *(bf16x8*)&Bs2[sidx * 8] = o;
        }
        __syncthreads();
        bf16x8 a[4], bb[2];
        #pragma unroll
        for (int fm = 0; fm < 4; ++fm)
            a[fm] = *(const bf16x8*)&Xs[(fm * 16 + frow) * 32 + swz];
        #pragma unroll
        for (int fn = 0; fn < 2; ++fn)
            bb[fn] = *(const bf16x8*)&Bs2[(fk * 128 + wn + fn * 16 + frow) * 8];
        #pragma unroll
        for (int fm = 0; fm < 4; ++fm)
            #pragma unroll
            for (int fn = 0; fn < 2; ++fn)
                acc[fm][fn] = __builtin_amdgcn_mfma_f32_16x16x32_bf16(
                    a[fm], bb[fn], acc[fm][fn], 0, 0, 0);
        __syncthreads();
    }

    unsigned short* st = statesbf + ((long long)(bz * NHEADS + h)) * HEADDIM * DSTATE;
    const int crow = (lane >> 4) * 4;
    const int ccol = lane & 15;
    #pragma unroll
    for (int fm = 0; fm < 4; ++fm)
        #pragma unroll
        for (int j = 0; j < 4; ++j) {
            int p = fm * 16 + crow + j;
            #pragma unroll
            for (int fn = 0; fn < 2; ++fn)
                st[p * DSTATE + wn + fn * 16 + ccol] = f2bf(acc[fm][fn][j]);
        }
}

// ============================================================
// Inter-chunk scan, bf16 in place: states[z] <- prev[z] (carry in fp32)
// ============================================================
__global__ __launch_bounds__(256)
void chunk_scan(unsigned short* __restrict__ states, const float* __restrict__ cs)
{
    int f = blockIdx.x * 256 + threadIdx.x;
    int n = f & 127;
    int p = (f >> 7) & 63;
    int h = (f >> 13) & 31;
    int b = f >> 18;

    float carry = 0.f;
    for (int z = 0; z < NC; ++z) {
        long long idx = ((((long long)(b * NC + z) * NHEADS) + h) * HEADDIM + p) * DSTATE + n;
        float st = bfu(states[idx]);
        states[idx] = f2bf(carry);
        float cd = expf(cs[((long long)(b * NHEADS) + h) * SEQ + z * CHUNK + CHUNK - 1]);
        carry = carry * cd + st;
    }
}

// ============================================================
// Fused Y, row-split: grid (1024, 2); block handles 128 rows of one (b,z,h).
// Xs staging coalesced + swizzled (involution).
// ============================================================
__global__ __launch_bounds__(256)
void y_fused(const unsigned short* __restrict__ Smat, const unsigned short* __restrict__ Cc,
             const unsigned short* __restrict__ xdT, const unsigned short* __restrict__ prevbf,
             const float* __restrict__ cs, const float* __restrict__ Dv,
             const unsigned short* __restrict__ xconv, unsigned short* __restrict__ y)
{
    const int h  = blockIdx.x & 31;
    const int bz = blockIdx.x >> 5;
    const int z  = bz & (NC - 1);
    const int b  = bz >> 4;
    const int r0 = blockIdx.y * 128;
    const int tid = threadIdx.x;
    const int lane = tid & 63;
    const int wid = tid >> 6;
    const int frow = lane & 15;
    const int fk = lane >> 4;
    const int wr = wid * 32;
    const int swz = (fk ^ ((frow >> 1) & 3)) * 8;

    __shared__ __attribute__((aligned(16))) short Ms[4 * 128 * 8];
    __shared__ __attribute__((aligned(16))) short Xs[64 * 32];
    __shared__ float css[CHUNK];

    const long long csbase = ((long long)(b * NHEADS) + h) * SEQ + (long long)z * CHUNK;
    const long long rowbase = (long long)b * SEQ + (long long)z * CHUNK;

    css[tid] = cs[csbase + tid];
    __syncthreads();

    const int lrow = tid & 127;
    const int grow = r0 + lrow;
    const int g0   = (tid >> 7) * 2;
    const float cl = css[grow];

    const int sp_ = tid >> 2;
    const int sc_ = (tid & 3) ^ ((tid >> 3) & 3);
    short* XsW = &Xs[(wid * 64) * 8];

    f32x4 acc[2][4];
    #pragma unroll
    for (int i = 0; i < 2; ++i)
        #pragma unroll
        for (int j = 0; j < 4; ++j) acc[i][j] = (f32x4)(0.0f);

    const unsigned short* Srow = Smat + ((long long)bz * CHUNK + grow) * CHUNK;
    const unsigned short* xdbase = xdT + (((long long)(b * NHEADS) + h) * 64) * SEQ + (long long)z * CHUNK;

    // ---- phase 1: masked-S (pairwise decay) @ xdT ----
    for (int s0 = 0; s0 < r0 + 128; s0 += 32) {
        gload16(xdbase + (long long)sp_ * SEQ + s0 + sc_ * 8, XsW);
        #pragma unroll
        for (int gg = 0; gg < 2; ++gg) {
            const int g = g0 + gg;
            bf16x8 o;
            if (s0 + g * 8 <= grow) {
                const unsigned short* sp = Srow + s0 + g * 8;
                ushort4 v0 = *(const ushort4*)sp;
                ushort4 v1 = *(const ushort4*)(sp + 4);
                unsigned short tv[8] = {v0.x, v0.y, v0.z, v0.w, v1.x, v1.y, v1.z, v1.w};
                #pragma unroll
                for (int j = 0; j < 8; ++j) {
                    int sg = s0 + g * 8 + j;
                    float m = (sg <= grow) ? bfu(tv[j]) * __expf(cl - css[sg]) : 0.f;
                    o[j] = (short)f2bf(m);
                }
            } else {
                #pragma unroll
                for (int j = 0; j < 8; ++j) o[j] = 0;
            }
            *(bf16x8*)&Ms[(g * 128 + lrow) * 8] = o;
        }
        __syncthreads();
        if (s0 <= r0 + wr + 31) {
            __builtin_amdgcn_s_setprio(1);
            bf16x8 a[2], bb[4];
            #pragma unroll
            for (int fm = 0; fm < 2; ++fm)
                a[fm] = *(const bf16x8*)&Ms[(fk * 128 + wr + fm * 16 + frow) * 8];
            #pragma unroll
            for (int fn = 0; fn < 4; ++fn)
                bb[fn] = *(const bf16x8*)&Xs[(fn * 16 + frow) * 32 + swz];
            #pragma unroll
            for (int fm = 0; fm < 2; ++fm)
                #pragma unroll
                for (int fn = 0; fn < 4; ++fn)
                    acc[fm][fn] = __builtin_amdgcn_mfma_f32_16x16x32_bf16(
                        a[fm], bb[fn], acc[fm][fn], 0, 0, 0);
            __builtin_amdgcn_s_setprio(0);
        }
        __syncthreads();
    }

    // ---- phase 2: (C*exp(cs_l)) @ prev ----
    const float el = __expf(cl);
    const unsigned short* Crow = Cc + (rowbase + grow) * DSTATE;
    const unsigned short* pvb = prevbf + (long long)(bz * NHEADS + h) * HEADDIM * DSTATE;
    for (int n0 = 0; n0 < DSTATE; n0 += 32) {
        gload16(pvb + (long long)sp_ * DSTATE + n0 + sc_ * 8, XsW);
        #pragma unroll
        for (int gg = 0; gg < 2; ++gg) {
            const int g = g0 + gg;
            const unsigned short* sp = Crow + n0 + g * 8;
            ushort4 v0 = *(const ushort4*)sp;
            ushort4 v1 = *(const ushort4*)(sp + 4);
            unsigned short tv[8] = {v0.x, v0.y, v0.z, v0.w, v1.x, v1.y, v1.z, v1.w};
            bf16x8 o;
            #pragma unroll
            for (int j = 0; j < 8; ++j) o[j] = (short)f2bf(bfu(tv[j]) * el);
            *(bf16x8*)&Ms[(g * 128 + lrow) * 8] = o;
        }
        __syncthreads();
        {
            __builtin_amdgcn_s_setprio(1);
            bf16x8 a[2], bb[4];
            #pragma unroll
            for (int fm = 0; fm < 2; ++fm)
                a[fm] = *(const bf16x8*)&Ms[(fk * 128 + wr + fm * 16 + frow) * 8];
            #pragma unroll
            for (int fn = 0; fn < 4; ++fn)
                bb[fn] = *(const bf16x8*)&Xs[(fn * 16 + frow) * 32 + swz];
            #pragma unroll
            for (int fm = 0; fm < 2; ++fm)
                #pragma unroll
                for (int fn = 0; fn < 4; ++fn)
                    acc[fm][fn] = __builtin_amdgcn_mfma_f32_16x16x32_bf16(
                        a[fm], bb[fn], acc[fm][fn], 0, 0, 0);
            __builtin_amdgcn_s_setprio(0);
        }
        __syncthreads();
    }

    // ---- epilogue: + D_h * x ----
    const float Dh = Dv[h];
    const int crow = (lane >> 4) * 4;
    const int ccol = lane & 15;
    #pragma unroll
    for (int fm = 0; fm < 2; ++fm) {
        #pragma unroll
        for (int j = 0; j < 4; ++j) {
            long long row = rowbase + r0 + wr + fm * 16 + crow + j;
            const unsigned short* xr = xconv + row * DSSM + h * 64;
            unsigned short* yr = y + row * DSSM + h * 64;
            #pragma unroll
            for (int fn = 0; fn < 4; ++fn) {
                int p = fn * 16 + ccol;
                yr[p] = f2bf(acc[fm][fn][j] + Dh * bfu(xr[p]));
            }
        }
    }
}

// ============================================================
__global__ __launch_bounds__(256)
void gated_rmsnorm(bf16* __restrict__ y, const bf16* __restrict__ z,
                   const float* __restrict__ nw)
{
    const int row = blockIdx.x;
    const int tid = threadIdx.x;
    bf16* yr = y + (long long)row * DSSM;
    const bf16* zr = z + (long long)row * DSSM;

    float t[8];
    float ss = 0.f;
    const int c0 = tid * 8;
    #pragma unroll
    for (int j = 0; j < 8; ++j) {
        float zv = __bfloat162float(zr[c0 + j]);
        float tv = __bfloat162float(yr[c0 + j]) * siluf(zv);
        t[j] = tv;
        ss += tv * tv;
    }
    #pragma unroll
    for (int off = 32; off > 0; off >>= 1) ss += __shfl_down(ss, off);
    __shared__ float red[4];
    if ((tid & 63) == 0) red[tid >> 6] = ss;
    __syncthreads();
    float tot = red[0] + red[1] + red[2] + red[3];
    float rs = rsqrtf(tot / (float)DSSM + EPSF);
    #pragma unroll
    for (int j = 0; j < 8; ++j)
        yr[c0 + j] = __float2bfloat16(t[j] * rs * nw[c0 + j]);
}

// ============================================================
extern "C" void kernel_launch(void* const* d_in, const int* in_sizes, int n_in,
                              void* d_out, int out_size, void* d_ws, size_t ws_size,
                              hipStream_t stream)
{
    const float* inp     = (const float*)d_in[0];
    const float* W_in    = (const float*)d_in[1];
    const float* conv_w  = (const float*)d_in[2];
    const float* conv_b  = (const float*)d_in[3];
    const float* dt_bias = (const float*)d_in[4];
    const float* A_log   = (const float*)d_in[5];
    const float* Dv      = (const float*)d_in[6];
    const float* norm_w  = (const float*)d_in[7];
    const float* W_out   = (const float*)d_in[8];
    float* out = (float*)d_out;

    char* ws = (char*)d_ws;
    size_t off = 0;
    auto alloc = [&](size_t bytes) -> void* {
        void* p = (void*)(ws + off);
        off = (off + bytes + 255) & ~(size_t)255;
        return p;
    };
    const int MR = B_SZ * SEQ;   // 8192 token rows

    bf16*  zb     = (bf16*) alloc((size_t)MR * DSSM * 2);            // 33.55 MB
    bf16*  xbc    = (bf16*) alloc((size_t)MR * CONVDIM * 2);         // 37.75 MB (dead after conv)
    bf16*  xconv  = (bf16*) alloc((size_t)MR * DSSM * 2);            // 33.55 MB
    bf16*  Bc     = (bf16*) alloc((size_t)MR * DSTATE * 2);          // 2.10 MB
    bf16*  Cc     = (bf16*) alloc((size_t)MR * DSTATE * 2);          // 2.10 MB
    float* dtraw  = (float*)alloc((size_t)MR * NHEADS * 4);          // 1.05 MB
    float* dtp    = (float*)alloc((size_t)MR * NHEADS * 4);          // 1.05 MB
    float* cs     = (float*)alloc((size_t)B_SZ * NHEADS * SEQ * 4);  // 1.05 MB
    unsigned short* statesbf = (unsigned short*)
                    alloc((size_t)B_SZ * NC * NHEADS * HEADDIM * DSTATE * 2);  // 16.78 MB
    unsigned short* Wob = (unsigned short*)alloc((size_t)DOUTSZ * DINNER * 2); // 4.19 MB
    unsigned short* xdT = (unsigned short*)alloc((size_t)B_SZ * NHEADS * 64 * SEQ * 2); // 33.55 MB
    // total ~167 MB

    // aliases (lifetime-disjoint, stream-ordered):
    bf16*  Smat = (bf16*)xbc;                                        // xbc head, after conv
    bf16*  ybuf = (bf16*)((char*)xbc + (size_t)B_SZ * NC * CHUNK * CHUNK * 2);
    unsigned short* BT   = (unsigned short*)ybuf;                    // dead before y_fused writes ybuf
    unsigned short* inpb = (unsigned short*)statesbf;                // dead before chunk_states writes
    unsigned short* Wb   = (unsigned short*)xconv;                   // dead before conv writes xconv

    dim3 blk(256);
    dim3 blk512(512);

    // 0) fused casts to bf16 (one launch): inp, W_in, W_out
    {
        const int n1 = (MR * DMODEL) / 2048;          // 4096
        const int n2 = (4384 * DMODEL) / 2048;        // 2192
        const int n3 = (DOUTSZ * DINNER) / 2048;      // 1024
        cast3_f32_bf16<<<dim3(n1 + n2 + n3), blk, 0, stream>>>(
            inp, inpb, n1, W_in, Wb, n2, W_out, Wob);
    }

    // 1) in_proj: merged z+xBC (N=4352) 256^2-tile 2-phase MFMA; dt fp32 tiled
    gemm256_nt<true, unsigned short><<<dim3((DSSM + CONVDIM) / 256, MR / 256), blk512, 0, stream>>>(
        (const short*)inpb, (const short*)Wb,
        (unsigned short*)zb, (unsigned short*)xbc, MR, DSSM + CONVDIM, DMODEL);
    dt_gemm_tiled<<<dim3(MR / 32), blk, 0, stream>>>(
        inp, W_in + (size_t)(DSSM + CONVDIM) * DMODEL, dtraw);

    // 2) conv + silu + split (vectorized; xbc dead afterwards)
    conv_silu_v2<<<dim3(CONVDIM / 256, MR / 8), blk, 0, stream>>>(
        (const unsigned short*)xbc, conv_w, conv_b,
        (unsigned short*)xconv, (unsigned short*)Bc, (unsigned short*)Cc);

    // 3) softplus + cumsum fused
    cumsum_da<<<dim3(B_SZ * NHEADS * NC), blk, 0, stream>>>(dtraw, dt_bias, A_log, dtp, cs);

    // 4) S = Cm @ Bm^T per (b,chunk) -> Smat (128^2 coalesced pipelined, batched)
    gemm_mfma_nt<unsigned short><<<dim3(CHUNK / 128, CHUNK / 128, B_SZ * NC), blk512, 0, stream>>>(
        (const short*)Cc, (const short*)Bc, (unsigned short*)Smat, CHUNK, CHUNK, DSTATE,
        (long long)CHUNK * DSTATE, (long long)CHUNK * DSTATE, (long long)CHUNK * CHUNK);

    // 5) xdT precompute (x * dtp, transposed)
    xdt_prep<<<dim3(SEQ / 128, NHEADS, B_SZ), blk, 0, stream>>>(
        (const unsigned short*)xconv, dtp, xdT);

    // 6) BT precompute (B transposed; aliases ybuf head, dead before step 9)
    bt_prep<<<dim3(SEQ / 128, B_SZ), blk, 0, stream>>>((const unsigned short*)Bc, BT);

    // 7) per-chunk states (MFMA, bf16 out; overwrites inpb region)
    chunk_states_mfma<<<dim3(B_SZ * NC * NHEADS), blk, 0, stream>>>(BT, xdT, cs, statesbf);

    // 8) inter-chunk scan (bf16 in place -> prev)
    chunk_scan<<<dim3(B_SZ * NHEADS * HEADDIM * DSTATE / 256), blk, 0, stream>>>(statesbf, cs);

    // 9) fused Y: Y_diag + Y_off + D*x -> ybuf (row-split, grid x2)
    y_fused<<<dim3(B_SZ * NC * NHEADS, 2), blk, 0, stream>>>(
        (const unsigned short*)Smat, (const unsigned short*)Cc, xdT, statesbf,
        cs, Dv, (const unsigned short*)xconv, (unsigned short*)ybuf);

    // 10) gated RMSNorm (in place on ybuf)
    gated_rmsnorm<<<dim3(MR), blk, 0, stream>>>(ybuf, zb, norm_w);

    // 11) out GEMM: 128^2 coalesced pipelined (512 blocks -> all CUs active)
    gemm_mfma_nt<float><<<dim3(DOUTSZ / 128, MR / 128), blk512, 0, stream>>>(
        (const short*)ybuf, (const short*)Wob, out, MR, DOUTSZ, DINNER, 0, 0, 0);
}

// Round 24
// 396.299 us; speedup vs baseline: 1.0770x; 1.0033x over previous
//
#include <hip/hip_runtime.h>
#include <hip/hip_bf16.h>
#include <math.h>

// ---- problem constants ----
#define B_SZ     2
#define SEQ      4096
#define DMODEL   1024
#define DSTATE   128
#define HEADDIM  64
#define CHUNK    256
#define DINNER   2048
#define DSSM     2048
#define NHEADS   32
#define CONVDIM  2304       // DSSM + 2*DSTATE
#define DOUTSZ   1024
#define NC       16         // SEQ / CHUNK
#define EPSF     1e-5f

typedef __hip_bfloat16 bf16;
typedef __attribute__((ext_vector_type(8))) short bf16x8;
typedef __attribute__((ext_vector_type(4))) float f32x4;

__device__ __forceinline__ float siluf(float x) { return x / (1.0f + expf(-x)); }

__device__ __forceinline__ float bfu(unsigned short u) {
    union { unsigned int i; float f; } c; c.i = ((unsigned int)u) << 16; return c.f;
}
__device__ __forceinline__ unsigned short f2bf(float f) {
    union { float f; unsigned int u; } c; c.f = f;
    unsigned int u = c.u;
    return (unsigned short)((u + 0x7FFFu + ((u >> 16) & 1u)) >> 16);
}

// async global(16B) -> LDS (wave-uniform base + lane*16; global addr per-lane)
__device__ __forceinline__ void gload16(const void* g, void* l) {
    typedef __attribute__((address_space(1))) const unsigned int GU;
    typedef __attribute__((address_space(3))) unsigned int LU;
    __builtin_amdgcn_global_load_lds((GU*)g, (LU*)l, 16, 0, 0);
}

// ============================================================
// fused fp32 -> bf16 cast over up to three regions, one launch.
// (now used for weights only: W_in, W_out)
// ============================================================
__global__ __launch_bounds__(256)
void cast3_f32_bf16(const float* __restrict__ s1, unsigned short* __restrict__ d1, int n1,
                    const float* __restrict__ s2, unsigned short* __restrict__ d2, int n2,
                    const float* __restrict__ s3, unsigned short* __restrict__ d3)
{
    int blk = blockIdx.x;
    const float* src; unsigned short* dst;
    if (blk < n1)            { src = s1; dst = d1; }
    else if (blk < n1 + n2)  { src = s2; dst = d2; blk -= n1; }
    else                     { src = s3; dst = d3; blk -= n1 + n2; }
    const long long i = ((long long)blk * 256 + threadIdx.x) * 8;
    float4 a = *(const float4*)(src + i);
    float4 b = *(const float4*)(src + i + 4);
    bf16x8 o;
    o[0] = (short)f2bf(a.x); o[1] = (short)f2bf(a.y);
    o[2] = (short)f2bf(a.z); o[3] = (short)f2bf(a.w);
    o[4] = (short)f2bf(b.x); o[5] = (short)f2bf(b.y);
    o[6] = (short)f2bf(b.z); o[7] = (short)f2bf(b.w);
    *(bf16x8*)(dst + i) = o;
}

// ============================================================
// 256x256-tile bf16 MFMA NT GEMM: BK=32, 8 waves, 2-phase dbuf, coalesced
// staging + XOR swizzle involution (rule #21). Proven 113 us @ inproj.
// ============================================================
template<bool SPLIT, typename TC>
__global__ __launch_bounds__(512)
void gemm256_nt(const short* __restrict__ A, const short* __restrict__ B,
                TC* __restrict__ C0, TC* __restrict__ C1, int M, int N, int K)
{
    const int nwg = gridDim.x * gridDim.y;
    const int orig = blockIdx.y * gridDim.x + blockIdx.x;
    const int q = nwg >> 3, r = nwg & 7;
    const int xcd = orig & 7, rest = orig >> 3;
    const int wgid = (xcd < r ? xcd * (q + 1) : r * (q + 1) + (xcd - r) * q) + rest;
    const int bx = wgid % gridDim.x;
    const int by = wgid / gridDim.x;

    __shared__ short As0[256 * 32];
    __shared__ short As1[256 * 32];
    __shared__ short Bs0[256 * 32];
    __shared__ short Bs1[256 * 32];

    const int tid  = threadIdx.x;
    const int lane = tid & 63;
    const int wid  = tid >> 6;
    const int wr = (wid >> 2) * 128;
    const int wc = (wid & 3) * 64;
    const int frow = lane & 15;
    const int fk   = lane >> 4;
    const int m0 = by * 256;
    const int n0 = bx * 256;

    const int s0 = tid, s1 = 512 + tid;
    const int r0s = s0 >> 2, c0s = (s0 & 3) ^ ((s0 >> 3) & 3);
    const int r1s = s1 >> 2, c1s = (s1 & 3) ^ ((s1 >> 3) & 3);
    const short* Ag0 = A + (long long)(m0 + r0s) * K + c0s * 8;
    const short* Ag1 = A + (long long)(m0 + r1s) * K + c1s * 8;
    const short* Bg0 = B + (long long)(n0 + r0s) * K + c0s * 8;
    const short* Bg1 = B + (long long)(n0 + r1s) * K + c1s * 8;

    short* A0w0 = &As0[(wid * 64) * 8];        short* A0w1 = &As0[(512 + wid * 64) * 8];
    short* A1w0 = &As1[(wid * 64) * 8];        short* A1w1 = &As1[(512 + wid * 64) * 8];
    short* B0w0 = &Bs0[(wid * 64) * 8];        short* B0w1 = &Bs0[(512 + wid * 64) * 8];
    short* B1w0 = &Bs1[(wid * 64) * 8];        short* B1w1 = &Bs1[(512 + wid * 64) * 8];

    const int swz = (fk ^ ((frow >> 1) & 3)) * 8;

    f32x4 acc[8][4];
    #pragma unroll
    for (int i = 0; i < 8; ++i)
        #pragma unroll
        for (int j = 0; j < 4; ++j) acc[i][j] = (f32x4)(0.0f);

    const int NT = K / 32;
    gload16(Ag0, A0w0); gload16(Ag1, A0w1);
    gload16(Bg0, B0w0); gload16(Bg1, B0w1);
    __syncthreads();

    int cur = 0;
    for (int t = 0; t < NT; ++t) {
        if (t + 1 < NT) {
            const int k = (t + 1) * 32;
            gload16(Ag0 + k, cur ? A0w0 : A1w0);
            gload16(Ag1 + k, cur ? A0w1 : A1w1);
            gload16(Bg0 + k, cur ? B0w0 : B1w0);
            gload16(Bg1 + k, cur ? B0w1 : B1w1);
        }
        const short* Asc = cur ? As1 : As0;
        const short* Bsc = cur ? Bs1 : Bs0;
        bf16x8 a[8], b[4];
        #pragma unroll
        for (int fm = 0; fm < 8; ++fm)
            a[fm] = *(const bf16x8*)&Asc[(wr + fm * 16 + frow) * 32 + swz];
        #pragma unroll
        for (int fn = 0; fn < 4; ++fn)
            b[fn] = *(const bf16x8*)&Bsc[(wc + fn * 16 + frow) * 32 + swz];
        #pragma unroll
        for (int fm = 0; fm < 8; ++fm)
            #pragma unroll
            for (int fn = 0; fn < 4; ++fn)
                acc[fm][fn] = __builtin_amdgcn_mfma_f32_16x16x32_bf16(
                    a[fm], b[fn], acc[fm][fn], 0, 0, 0);
        __syncthreads();
        cur ^= 1;
    }

    const int crow = (lane >> 4) * 4;
    const int ccol = lane & 15;
    #pragma unroll
    for (int fm = 0; fm < 8; ++fm) {
        #pragma unroll
        for (int j = 0; j < 4; ++j) {
            long long row = m0 + wr + fm * 16 + crow + j;
            #pragma unroll
            for (int fn = 0; fn < 4; ++fn) {
                int col = n0 + wc + fn * 16 + ccol;
                float v = acc[fm][fn][j];
                if constexpr (SPLIT) {
                    if (col < DSSM)
                        C0[row * DSSM + col] = (TC)f2bf(v);
                    else
                        C1[row * CONVDIM + (col - DSSM)] = (TC)f2bf(v);
                } else {
                    if constexpr (sizeof(TC) == 2) C0[row * N + col] = (TC)f2bf(v);
                    else                           C0[row * N + col] = v;
                }
            }
        }
    }
}

// ============================================================
// 128x128 8-wave pipelined MFMA NT GEMM (Smat batched + out GEMM),
// coalesced staging + XOR swizzle, 3-buf counted-vmcnt pipeline.
// ============================================================
#define G8_DECLS()                                                                \
    __shared__ short As0[128 * 32];                                               \
    __shared__ short As1[128 * 32];                                               \
    __shared__ short As2[128 * 32];                                               \
    __shared__ short Bs0[128 * 32];                                               \
    __shared__ short Bs1[128 * 32];                                               \
    __shared__ short Bs2[128 * 32];                                               \
    const int tid  = threadIdx.x;                                                 \
    const int lane = tid & 63;                                                    \
    const int wid  = tid >> 6;                                                    \
    const int wr = (wid >> 2) * 64;                                               \
    const int wc = (wid & 3) * 32;                                                \
    const int srow = tid >> 2;                                                    \
    const int schk = (tid & 3) ^ ((tid >> 3) & 3);                                \
    short* AsW0 = &As0[(wid * 64) * 8];                                           \
    short* AsW1 = &As1[(wid * 64) * 8];                                           \
    short* AsW2 = &As2[(wid * 64) * 8];                                           \
    short* BsW0 = &Bs0[(wid * 64) * 8];                                           \
    short* BsW1 = &Bs1[(wid * 64) * 8];                                           \
    short* BsW2 = &Bs2[(wid * 64) * 8];                                           \
    const int frow = lane & 15;                                                   \
    const int fk   = lane >> 4;                                                   \
    const int swz  = (fk ^ ((frow >> 1) & 3)) * 8;

#define G8_PIPE(K_)                                                               \
    {                                                                             \
        const int NT = (K_) / 32;                                                 \
        gload16(Ag + 0 * 32, AsW0); gload16(Bg + 0 * 32, BsW0);                   \
        gload16(Ag + 1 * 32, AsW1); gload16(Bg + 1 * 32, BsW1);                   \
        gload16(Ag + 2 * 32, AsW2); gload16(Bg + 2 * 32, BsW2);                   \
        asm volatile("s_waitcnt vmcnt(4)" ::: "memory");                          \
        __builtin_amdgcn_sched_barrier(0);                                        \
        __builtin_amdgcn_s_barrier();                                             \
        for (int t = 0; t < NT; ++t) {                                            \
            const int cur = t % 3;                                                \
            const short* Asc = cur == 0 ? As0 : (cur == 1 ? As1 : As2);           \
            const short* Bsc = cur == 0 ? Bs0 : (cur == 1 ? Bs1 : Bs2);           \
            bf16x8 a[4], b[2];                                                    \
            _Pragma("unroll")                                                     \
            for (int fm = 0; fm < 4; ++fm)                                        \
                a[fm] = *(const bf16x8*)&Asc[(wr + fm * 16 + frow) * 32 + swz];   \
            _Pragma("unroll")                                                     \
            for (int fn = 0; fn < 2; ++fn)                                        \
                b[fn] = *(const bf16x8*)&Bsc[(wc + fn * 16 + frow) * 32 + swz];   \
            _Pragma("unroll")                                                     \
            for (int fm = 0; fm < 4; ++fm)                                        \
                _Pragma("unroll")                                                 \
                for (int fn = 0; fn < 2; ++fn)                                    \
                    acc[fm][fn] = __builtin_amdgcn_mfma_f32_16x16x32_bf16(        \
                        a[fm], b[fn], acc[fm][fn], 0, 0, 0);                      \
            __builtin_amdgcn_s_barrier();                                         \
            if (t + 3 < NT) {                                                     \
                short* stA = cur == 0 ? AsW0 : (cur == 1 ? AsW1 : AsW2);          \
                short* stB = cur == 0 ? BsW0 : (cur == 1 ? BsW1 : BsW2);          \
                gload16(Ag + (t + 3) * 32, stA);                                  \
                gload16(Bg + (t + 3) * 32, stB);                                  \
                asm volatile("s_waitcnt vmcnt(4)" ::: "memory");                  \
            } else if (t + 2 < NT) {                                              \
                asm volatile("s_waitcnt vmcnt(2)" ::: "memory");                  \
            } else if (t + 1 < NT) {                                              \
                asm volatile("s_waitcnt vmcnt(0)" ::: "memory");                  \
            }                                                                     \
            __builtin_amdgcn_sched_barrier(0);                                    \
            __builtin_amdgcn_s_barrier();                                         \
        }                                                                         \
    }

template<typename TC>
__global__ __launch_bounds__(512)
void gemm_mfma_nt(const short* __restrict__ A, const short* __restrict__ B,
                  TC* __restrict__ C, int M, int N, int K,
                  long long sA, long long sB, long long sC)
{
    A += (long long)blockIdx.z * sA;
    B += (long long)blockIdx.z * sB;
    C += (long long)blockIdx.z * sC;

    const int nwg = gridDim.x * gridDim.y;
    const int orig = blockIdx.y * gridDim.x + blockIdx.x;
    const int q = nwg >> 3, r = nwg & 7;
    const int xcd = orig & 7, rest = orig >> 3;
    const int wgid = (xcd < r ? xcd * (q + 1) : r * (q + 1) + (xcd - r) * q) + rest;
    const int bx = wgid % gridDim.x;
    const int by = wgid / gridDim.x;

    G8_DECLS()

    const int m0 = by * 128;
    const int n0 = bx * 128;
    const short* Ag = A + (long long)(m0 + srow) * K + schk * 8;
    const short* Bg = B + (long long)(n0 + srow) * K + schk * 8;

    f32x4 acc[4][2];
    #pragma unroll
    for (int i = 0; i < 4; ++i) { acc[i][0] = (f32x4)(0.f); acc[i][1] = (f32x4)(0.f); }

    G8_PIPE(K)

    const int crow = (lane >> 4) * 4;
    const int ccol = lane & 15;
    #pragma unroll
    for (int fm = 0; fm < 4; ++fm) {
        #pragma unroll
        for (int j = 0; j < 4; ++j) {
            long long row = m0 + wr + fm * 16 + crow + j;
            TC* cp = C + row * N + n0 + wc + ccol;
            #pragma unroll
            for (int fn = 0; fn < 2; ++fn) {
                float v = acc[fm][fn][j];
                if constexpr (sizeof(TC) == 2) cp[fn * 16] = (TC)f2bf(v);
                else                           cp[fn * 16] = v;
            }
        }
    }
}

// ============================================================
// dt column GEMM (fp32): dtraw[m][h] = dot(inp[m], Wdt[h])
// FUSED: also writes the bf16 cast of each staged inp tile to inpb
// (saves cast3 re-reading all 32 MB of inp). Il padded to 132 so every
// row is 16B-aligned for the vec8 writeback.
// ============================================================
__global__ __launch_bounds__(256)
void dt_gemm_tiled(const float* __restrict__ inp, const float* __restrict__ Wdt,
                   float* __restrict__ dtraw, unsigned short* __restrict__ inpb)
{
    const int tid  = threadIdx.x;
    const int row0 = blockIdx.x * 32;
    const int hh   = (tid & 15) * 2;
    const int rr   = (tid >> 4) * 2;

    __shared__ float Wl[32][130];
    __shared__ float Il[32][132];

    float a00 = 0.f, a01 = 0.f, a10 = 0.f, a11 = 0.f;

    for (int k0 = 0; k0 < DMODEL; k0 += 128) {
        #pragma unroll
        for (int it = 0; it < 16; ++it) {
            int idx = it * 256 + tid;
            int r = idx >> 7, c = idx & 127;
            Wl[r][c] = Wdt[(long long)r * DMODEL + k0 + c];
            Il[r][c] = inp[(long long)(row0 + r) * DMODEL + k0 + c];
        }
        __syncthreads();
        // fused inp -> bf16 writeback (32 rows x 128 cols = 512 vec8; 2/thread)
        #pragma unroll
        for (int it = 0; it < 2; ++it) {
            int idx = it * 256 + tid;
            int r = idx >> 4, c = (idx & 15) * 8;
            float4 a = *(const float4*)&Il[r][c];
            float4 b = *(const float4*)&Il[r][c + 4];
            bf16x8 o;
            o[0] = (short)f2bf(a.x); o[1] = (short)f2bf(a.y);
            o[2] = (short)f2bf(a.z); o[3] = (short)f2bf(a.w);
            o[4] = (short)f2bf(b.x); o[5] = (short)f2bf(b.y);
            o[6] = (short)f2bf(b.z); o[7] = (short)f2bf(b.w);
            *(bf16x8*)(inpb + (long long)(row0 + r) * DMODEL + k0 + c) = o;
        }
        #pragma unroll
        for (int kk = 0; kk < 128; kk += 4) {
            float4 w0 = *(const float4*)&Wl[hh][kk];
            float4 w1 = *(const float4*)&Wl[hh + 1][kk];
            float4 i0 = *(const float4*)&Il[rr][kk];
            float4 i1 = *(const float4*)&Il[rr + 1][kk];
            a00 += i0.x * w0.x + i0.y * w0.y + i0.z * w0.z + i0.w * w0.w;
            a01 += i0.x * w1.x + i0.y * w1.y + i0.z * w1.z + i0.w * w1.w;
            a10 += i1.x * w0.x + i1.y * w0.y + i1.z * w0.z + i1.w * w0.w;
            a11 += i1.x * w1.x + i1.y * w1.y + i1.z * w1.z + i1.w * w1.w;
        }
        __syncthreads();
    }
    dtraw[(long long)(row0 + rr) * NHEADS + hh]         = a00;
    dtraw[(long long)(row0 + rr) * NHEADS + hh + 1]     = a01;
    dtraw[(long long)(row0 + rr + 1) * NHEADS + hh]     = a10;
    dtraw[(long long)(row0 + rr + 1) * NHEADS + hh + 1] = a11;
}

// ============================================================
// Depthwise causal conv (width 4) + bias + SiLU; vectorized bf16x8.
// ============================================================
__global__ __launch_bounds__(256)
void conv_silu_v2(const unsigned short* __restrict__ xbc, const float* __restrict__ cw,
                  const float* __restrict__ cb,
                  unsigned short* __restrict__ xconv, unsigned short* __restrict__ Bc,
                  unsigned short* __restrict__ Cc)
{
    const int tid = threadIdx.x;
    const int c8  = (blockIdx.x * 32 + (tid & 31)) * 8;
    const int lf  = blockIdx.y * 8 + (tid >> 5);
    const int b   = lf >> 12;
    const int l   = lf & (SEQ - 1);

    float4 w[8];
    #pragma unroll
    for (int j = 0; j < 8; ++j) w[j] = *(const float4*)(cw + (c8 + j) * 4);

    float acc[8];
    {
        float4 b0 = *(const float4*)(cb + c8);
        float4 b1 = *(const float4*)(cb + c8 + 4);
        acc[0] = b0.x; acc[1] = b0.y; acc[2] = b0.z; acc[3] = b0.w;
        acc[4] = b1.x; acc[5] = b1.y; acc[6] = b1.z; acc[7] = b1.w;
    }
    #pragma unroll
    for (int k = 0; k < 4; ++k) {
        int ls = l - 3 + k;
        if (ls < 0) continue;
        const unsigned short* src = xbc + ((long long)(b * SEQ + ls)) * CONVDIM + c8;
        ushort4 v0 = *(const ushort4*)src;
        ushort4 v1 = *(const ushort4*)(src + 4);
        unsigned short tv[8] = {v0.x, v0.y, v0.z, v0.w, v1.x, v1.y, v1.z, v1.w};
        #pragma unroll
        for (int j = 0; j < 8; ++j) {
            const float* wj = (const float*)&w[j];
            acc[j] += bfu(tv[j]) * wj[k];
        }
    }
    bf16x8 o;
    #pragma unroll
    for (int j = 0; j < 8; ++j) {
        float v = acc[j];
        v = v / (1.0f + __expf(-v));
        o[j] = (short)f2bf(v);
    }
    if (c8 < DSSM)
        *(bf16x8*)(xconv + (long long)lf * DSSM + c8) = o;
    else if (c8 < DSSM + DSTATE)
        *(bf16x8*)(Bc + (long long)lf * DSTATE + (c8 - DSSM)) = o;
    else
        *(bf16x8*)(Cc + (long long)lf * DSTATE + (c8 - DSSM - DSTATE)) = o;
}

// ============================================================
// cumsum of dA per (b,h,chunk), with fused softplus (writes dtp too)
// ============================================================
__global__ __launch_bounds__(256)
void cumsum_da(const float* __restrict__ dtraw, const float* __restrict__ dt_bias,
               const float* __restrict__ A_log, float* __restrict__ dtp,
               float* __restrict__ cs)
{
    const int bid = blockIdx.x;
    const int z = bid % NC;
    const int h = (bid / NC) % NHEADS;
    const int b = bid / (NC * NHEADS);
    const int t = threadIdx.x;

    const float Ah = -expf(A_log[h]);
    const int lg = z * CHUNK + t;
    const long long fi = ((long long)(b * SEQ) + lg) * NHEADS + h;
    float x = dtraw[fi] + dt_bias[h];
    float sp = (x > 20.f) ? x : log1pf(expf(x));
    dtp[fi] = sp;
    float v = sp * Ah;

    __shared__ float s[CHUNK];
    s[t] = v;
    __syncthreads();
    for (int off = 1; off < CHUNK; off <<= 1) {
        float add = (t >= off) ? s[t - off] : 0.f;
        __syncthreads();
        s[t] += add;
        __syncthreads();
    }
    cs[((long long)(b * NHEADS) + h) * SEQ + lg] = s[t];
}

// ============================================================
// xdT[b,h,p,s] = xconv[s, h*64+p] * dtp[s,h]   (transposed)
// ============================================================
__global__ __launch_bounds__(256)
void xdt_prep(const unsigned short* __restrict__ xconv, const float* __restrict__ dtp,
              unsigned short* __restrict__ xdT)
{
    const int st = blockIdx.x;
    const int h  = blockIdx.y;
    const int b  = blockIdx.z;
    const int tid = threadIdx.x;
    const int s0t = st * 128;

    __shared__ short T[128][66];
    __shared__ float scale[128];

    if (tid < 128) {
        int sg = s0t + tid;
        scale[tid] = dtp[((long long)(b * SEQ) + sg) * NHEADS + h];
    }
    __syncthreads();

    #pragma unroll
    for (int it = 0; it < 4; ++it) {
        int c = it * 256 + tid;
        int row = c >> 3, pc = c & 7;
        const unsigned short* src =
            xconv + ((long long)(b * SEQ) + s0t + row) * DSSM + h * 64 + pc * 8;
        ushort4 v0 = *(const ushort4*)src;
        ushort4 v1 = *(const ushort4*)(src + 4);
        float sc = scale[row];
        unsigned short tv[8] = {v0.x, v0.y, v0.z, v0.w, v1.x, v1.y, v1.z, v1.w};
        #pragma unroll
        for (int j = 0; j < 8; ++j) T[row][pc * 8 + j] = (short)f2bf(bfu(tv[j]) * sc);
    }
    __syncthreads();

    #pragma unroll
    for (int it = 0; it < 4; ++it) {
        int c = it * 256 + tid;
        int p = c >> 4, scc = c & 15;
        bf16x8 o;
        #pragma unroll
        for (int j = 0; j < 8; ++j) o[j] = T[scc * 8 + j][p];
        *(bf16x8*)(xdT + (((long long)(b * NHEADS) + h) * 64 + p) * SEQ + s0t + scc * 8) = o;
    }
}

// ============================================================
// BT[b][n][s] = Bc[b*SEQ+s][n]  (bf16 transpose)
// ============================================================
__global__ __launch_bounds__(256)
void bt_prep(const unsigned short* __restrict__ Bc, unsigned short* __restrict__ BT)
{
    const int st = blockIdx.x;
    const int b  = blockIdx.y;
    const int tid = threadIdx.x;
    const int s0t = st * 128;

    __shared__ short T[128][130];

    #pragma unroll
    for (int it = 0; it < 8; ++it) {
        int c = it * 256 + tid;
        int row = c >> 4, nc = c & 15;
        const unsigned short* src = Bc + ((long long)(b * SEQ) + s0t + row) * DSTATE + nc * 8;
        ushort4 v0 = *(const ushort4*)src;
        ushort4 v1 = *(const ushort4*)(src + 4);
        T[row][nc * 8 + 0] = v0.x; T[row][nc * 8 + 1] = v0.y;
        T[row][nc * 8 + 2] = v0.z; T[row][nc * 8 + 3] = v0.w;
        T[row][nc * 8 + 4] = v1.x; T[row][nc * 8 + 5] = v1.y;
        T[row][nc * 8 + 6] = v1.z; T[row][nc * 8 + 7] = v1.w;
    }
    __syncthreads();

    #pragma unroll
    for (int it = 0; it < 8; ++it) {
        int c = it * 256 + tid;
        int n = c >> 4, scc = c & 15;
        bf16x8 o;
        #pragma unroll
        for (int j = 0; j < 8; ++j) o[j] = T[scc * 8 + j][n];
        *(bf16x8*)(BT + ((long long)b * DSTATE + n) * SEQ + s0t + scc * 8) = o;
    }
}

// ============================================================
// chunk_states (MFMA): states[p,n] = sum_l xdT[p,l] * B[l,n] * dec[l]
// Xs staging coalesced + swizzled (involution).
// ============================================================
__global__ __launch_bounds__(256)
void chunk_states_mfma(const unsigned short* __restrict__ BT,
                       const unsigned short* __restrict__ xdT,
                       const float* __restrict__ cs,
                       unsigned short* __restrict__ statesbf)
{
    const int h  = blockIdx.x & 31;
    const int bz = blockIdx.x >> 5;
    const int z  = bz & (NC - 1);
    const int b  = bz >> 4;
    const int tid = threadIdx.x;
    const int lane = tid & 63;
    const int wid = tid >> 6;
    const int frow = lane & 15;
    const int fk = lane >> 4;
    const int wn = wid * 32;
    const int swz = (fk ^ ((frow >> 1) & 3)) * 8;

    __shared__ __attribute__((aligned(16))) short Xs[64 * 32];       // xdT tile [64p][32l]
    __shared__ __attribute__((aligned(16))) short Bs2[4 * 128 * 8];  // B*dec segs
    __shared__ float dec[CHUNK];

    const long long csbase = ((long long)(b * NHEADS) + h) * SEQ + (long long)z * CHUNK;
    {
        float clast = cs[csbase + CHUNK - 1];
        dec[tid] = __expf(clast - cs[csbase + tid]);   // exponent <= 0, safe
    }
    __syncthreads();

    f32x4 acc[4][2];
    #pragma unroll
    for (int i = 0; i < 4; ++i) { acc[i][0] = (f32x4)(0.f); acc[i][1] = (f32x4)(0.f); }

    const unsigned short* xdbase = xdT + (((long long)(b * NHEADS) + h) * 64) * SEQ + (long long)z * CHUNK;
    const unsigned short* btbase = BT + (long long)b * DSTATE * SEQ + (long long)z * CHUNK;

    const int sp_ = tid >> 2;
    const int sc_ = (tid & 3) ^ ((tid >> 3) & 3);
    short* XsW = &Xs[(wid * 64) * 8];

    for (int l0 = 0; l0 < CHUNK; l0 += 32) {
        gload16(xdbase + (long long)sp_ * SEQ + l0 + sc_ * 8, XsW);
        #pragma unroll
        for (int r = 0; r < 2; ++r) {
            int sidx = r * 256 + tid;
            int n = sidx & 127, lseg = sidx >> 7;
            const unsigned short* sp = btbase + (long long)n * SEQ + l0 + lseg * 8;
            ushort4 v0 = *(const ushort4*)sp;
            ushort4 v1 = *(const ushort4*)(sp + 4);
            unsigned short tv[8] = {v0.x, v0.y, v0.z, v0.w, v1.x, v1.y, v1.z, v1.w};
            bf16x8 o;
            #pragma unroll
            for (int j = 0; j < 8; ++j)
                o[j] = (short)f2bf(bfu(tv[j]) * dec[l0 + lseg * 8 + j]);
            *(bf16x8*)&Bs2[sidx * 8] = o;
        }
        __syncthreads();
        bf16x8 a[4], bb[2];
        #pragma unroll
        for (int fm = 0; fm < 4; ++fm)
            a[fm] = *(const bf16x8*)&Xs[(fm * 16 + frow) * 32 + swz];
        #pragma unroll
        for (int fn = 0; fn < 2; ++fn)
            bb[fn] = *(const bf16x8*)&Bs2[(fk * 128 + wn + fn * 16 + frow) * 8];
        #pragma unroll
        for (int fm = 0; fm < 4; ++fm)
            #pragma unroll
            for (int fn = 0; fn < 2; ++fn)
                acc[fm][fn] = __builtin_amdgcn_mfma_f32_16x16x32_bf16(
                    a[fm], bb[fn], acc[fm][fn], 0, 0, 0);
        __syncthreads();
    }

    unsigned short* st = statesbf + ((long long)(bz * NHEADS + h)) * HEADDIM * DSTATE;
    const int crow = (lane >> 4) * 4;
    const int ccol = lane & 15;
    #pragma unroll
    for (int fm = 0; fm < 4; ++fm)
        #pragma unroll
        for (int j = 0; j < 4; ++j) {
            int p = fm * 16 + crow + j;
            #pragma unroll
            for (int fn = 0; fn < 2; ++fn)
                st[p * DSTATE + wn + fn * 16 + ccol] = f2bf(acc[fm][fn][j]);
        }
}

// ============================================================
// Inter-chunk scan, bf16 in place: states[z] <- prev[z] (carry in fp32)
// ============================================================
__global__ __launch_bounds__(256)
void chunk_scan(unsigned short* __restrict__ states, const float* __restrict__ cs)
{
    int f = blockIdx.x * 256 + threadIdx.x;
    int n = f & 127;
    int p = (f >> 7) & 63;
    int h = (f >> 13) & 31;
    int b = f >> 18;

    float carry = 0.f;
    for (int z = 0; z < NC; ++z) {
        long long idx = ((((long long)(b * NC + z) * NHEADS) + h) * HEADDIM + p) * DSTATE + n;
        float st = bfu(states[idx]);
        states[idx] = f2bf(carry);
        float cd = expf(cs[((long long)(b * NHEADS) + h) * SEQ + z * CHUNK + CHUNK - 1]);
        carry = carry * cd + st;
    }
}

// ============================================================
// Fused Y, row-split: grid (1024, 2); block handles 128 rows of one (b,z,h).
// Xs staging coalesced + swizzled (involution).
// ============================================================
__global__ __launch_bounds__(256)
void y_fused(const unsigned short* __restrict__ Smat, const unsigned short* __restrict__ Cc,
             const unsigned short* __restrict__ xdT, const unsigned short* __restrict__ prevbf,
             const float* __restrict__ cs, const float* __restrict__ Dv,
             const unsigned short* __restrict__ xconv, unsigned short* __restrict__ y)
{
    const int h  = blockIdx.x & 31;
    const int bz = blockIdx.x >> 5;
    const int z  = bz & (NC - 1);
    const int b  = bz >> 4;
    const int r0 = blockIdx.y * 128;
    const int tid = threadIdx.x;
    const int lane = tid & 63;
    const int wid = tid >> 6;
    const int frow = lane & 15;
    const int fk = lane >> 4;
    const int wr = wid * 32;
    const int swz = (fk ^ ((frow >> 1) & 3)) * 8;

    __shared__ __attribute__((aligned(16))) short Ms[4 * 128 * 8];
    __shared__ __attribute__((aligned(16))) short Xs[64 * 32];
    __shared__ float css[CHUNK];

    const long long csbase = ((long long)(b * NHEADS) + h) * SEQ + (long long)z * CHUNK;
    const long long rowbase = (long long)b * SEQ + (long long)z * CHUNK;

    css[tid] = cs[csbase + tid];
    __syncthreads();

    const int lrow = tid & 127;
    const int grow = r0 + lrow;
    const int g0   = (tid >> 7) * 2;
    const float cl = css[grow];

    const int sp_ = tid >> 2;
    const int sc_ = (tid & 3) ^ ((tid >> 3) & 3);
    short* XsW = &Xs[(wid * 64) * 8];

    f32x4 acc[2][4];
    #pragma unroll
    for (int i = 0; i < 2; ++i)
        #pragma unroll
        for (int j = 0; j < 4; ++j) acc[i][j] = (f32x4)(0.0f);

    const unsigned short* Srow = Smat + ((long long)bz * CHUNK + grow) * CHUNK;
    const unsigned short* xdbase = xdT + (((long long)(b * NHEADS) + h) * 64) * SEQ + (long long)z * CHUNK;

    // ---- phase 1: masked-S (pairwise decay) @ xdT ----
    for (int s0 = 0; s0 < r0 + 128; s0 += 32) {
        gload16(xdbase + (long long)sp_ * SEQ + s0 + sc_ * 8, XsW);
        #pragma unroll
        for (int gg = 0; gg < 2; ++gg) {
            const int g = g0 + gg;
            bf16x8 o;
            if (s0 + g * 8 <= grow) {
                const unsigned short* sp = Srow + s0 + g * 8;
                ushort4 v0 = *(const ushort4*)sp;
                ushort4 v1 = *(const ushort4*)(sp + 4);
                unsigned short tv[8] = {v0.x, v0.y, v0.z, v0.w, v1.x, v1.y, v1.z, v1.w};
                #pragma unroll
                for (int j = 0; j < 8; ++j) {
                    int sg = s0 + g * 8 + j;
                    float m = (sg <= grow) ? bfu(tv[j]) * __expf(cl - css[sg]) : 0.f;
                    o[j] = (short)f2bf(m);
                }
            } else {
                #pragma unroll
                for (int j = 0; j < 8; ++j) o[j] = 0;
            }
            *(bf16x8*)&Ms[(g * 128 + lrow) * 8] = o;
        }
        __syncthreads();
        if (s0 <= r0 + wr + 31) {
            __builtin_amdgcn_s_setprio(1);
            bf16x8 a[2], bb[4];
            #pragma unroll
            for (int fm = 0; fm < 2; ++fm)
                a[fm] = *(const bf16x8*)&Ms[(fk * 128 + wr + fm * 16 + frow) * 8];
            #pragma unroll
            for (int fn = 0; fn < 4; ++fn)
                bb[fn] = *(const bf16x8*)&Xs[(fn * 16 + frow) * 32 + swz];
            #pragma unroll
            for (int fm = 0; fm < 2; ++fm)
                #pragma unroll
                for (int fn = 0; fn < 4; ++fn)
                    acc[fm][fn] = __builtin_amdgcn_mfma_f32_16x16x32_bf16(
                        a[fm], bb[fn], acc[fm][fn], 0, 0, 0);
            __builtin_amdgcn_s_setprio(0);
        }
        __syncthreads();
    }

    // ---- phase 2: (C*exp(cs_l)) @ prev ----
    const float el = __expf(cl);
    const unsigned short* Crow = Cc + (rowbase + grow) * DSTATE;
    const unsigned short* pvb = prevbf + (long long)(bz * NHEADS + h) * HEADDIM * DSTATE;
    for (int n0 = 0; n0 < DSTATE; n0 += 32) {
        gload16(pvb + (long long)sp_ * DSTATE + n0 + sc_ * 8, XsW);
        #pragma unroll
        for (int gg = 0; gg < 2; ++gg) {
            const int g = g0 + gg;
            const unsigned short* sp = Crow + n0 + g * 8;
            ushort4 v0 = *(const ushort4*)sp;
            ushort4 v1 = *(const ushort4*)(sp + 4);
            unsigned short tv[8] = {v0.x, v0.y, v0.z, v0.w, v1.x, v1.y, v1.z, v1.w};
            bf16x8 o;
            #pragma unroll
            for (int j = 0; j < 8; ++j) o[j] = (short)f2bf(bfu(tv[j]) * el);
            *(bf16x8*)&Ms[(g * 128 + lrow) * 8] = o;
        }
        __syncthreads();
        {
            __builtin_amdgcn_s_setprio(1);
            bf16x8 a[2], bb[4];
            #pragma unroll
            for (int fm = 0; fm < 2; ++fm)
                a[fm] = *(const bf16x8*)&Ms[(fk * 128 + wr + fm * 16 + frow) * 8];
            #pragma unroll
            for (int fn = 0; fn < 4; ++fn)
                bb[fn] = *(const bf16x8*)&Xs[(fn * 16 + frow) * 32 + swz];
            #pragma unroll
            for (int fm = 0; fm < 2; ++fm)
                #pragma unroll
                for (int fn = 0; fn < 4; ++fn)
                    acc[fm][fn] = __builtin_amdgcn_mfma_f32_16x16x32_bf16(
                        a[fm], bb[fn], acc[fm][fn], 0, 0, 0);
            __builtin_amdgcn_s_setprio(0);
        }
        __syncthreads();
    }

    // ---- epilogue: + D_h * x ----
    const float Dh = Dv[h];
    const int crow = (lane >> 4) * 4;
    const int ccol = lane & 15;
    #pragma unroll
    for (int fm = 0; fm < 2; ++fm) {
        #pragma unroll
        for (int j = 0; j < 4; ++j) {
            long long row = rowbase + r0 + wr + fm * 16 + crow + j;
            const unsigned short* xr = xconv + row * DSSM + h * 64;
            unsigned short* yr = y + row * DSSM + h * 64;
            #pragma unroll
            for (int fn = 0; fn < 4; ++fn) {
                int p = fn * 16 + ccol;
                yr[p] = f2bf(acc[fm][fn][j] + Dh * bfu(xr[p]));
            }
        }
    }
}

// ============================================================
__global__ __launch_bounds__(256)
void gated_rmsnorm(bf16* __restrict__ y, const bf16* __restrict__ z,
                   const float* __restrict__ nw)
{
    const int row = blockIdx.x;
    const int tid = threadIdx.x;
    bf16* yr = y + (long long)row * DSSM;
    const bf16* zr = z + (long long)row * DSSM;

    float t[8];
    float ss = 0.f;
    const int c0 = tid * 8;
    #pragma unroll
    for (int j = 0; j < 8; ++j) {
        float zv = __bfloat162float(zr[c0 + j]);
        float tv = __bfloat162float(yr[c0 + j]) * siluf(zv);
        t[j] = tv;
        ss += tv * tv;
    }
    #pragma unroll
    for (int off = 32; off > 0; off >>= 1) ss += __shfl_down(ss, off);
    __shared__ float red[4];
    if ((tid & 63) == 0) red[tid >> 6] = ss;
    __syncthreads();
    float tot = red[0] + red[1] + red[2] + red[3];
    float rs = rsqrtf(tot / (float)DSSM + EPSF);
    #pragma unroll
    for (int j = 0; j < 8; ++j)
        yr[c0 + j] = __float2bfloat16(t[j] * rs * nw[c0 + j]);
}

// ============================================================
extern "C" void kernel_launch(void* const* d_in, const int* in_sizes, int n_in,
                              void* d_out, int out_size, void* d_ws, size_t ws_size,
                              hipStream_t stream)
{
    const float* inp     = (const float*)d_in[0];
    const float* W_in    = (const float*)d_in[1];
    const float* conv_w  = (const float*)d_in[2];
    const float* conv_b  = (const float*)d_in[3];
    const float* dt_bias = (const float*)d_in[4];
    const float* A_log   = (const float*)d_in[5];
    const float* Dv      = (const float*)d_in[6];
    const float* norm_w  = (const float*)d_in[7];
    const float* W_out   = (const float*)d_in[8];
    float* out = (float*)d_out;

    char* ws = (char*)d_ws;
    size_t off = 0;
    auto alloc = [&](size_t bytes) -> void* {
        void* p = (void*)(ws + off);
        off = (off + bytes + 255) & ~(size_t)255;
        return p;
    };
    const int MR = B_SZ * SEQ;   // 8192 token rows

    bf16*  zb     = (bf16*) alloc((size_t)MR * DSSM * 2);            // 33.55 MB
    bf16*  xbc    = (bf16*) alloc((size_t)MR * CONVDIM * 2);         // 37.75 MB (dead after conv)
    bf16*  xconv  = (bf16*) alloc((size_t)MR * DSSM * 2);            // 33.55 MB
    bf16*  Bc     = (bf16*) alloc((size_t)MR * DSTATE * 2);          // 2.10 MB
    bf16*  Cc     = (bf16*) alloc((size_t)MR * DSTATE * 2);          // 2.10 MB
    float* dtraw  = (float*)alloc((size_t)MR * NHEADS * 4);          // 1.05 MB
    float* dtp    = (float*)alloc((size_t)MR * NHEADS * 4);          // 1.05 MB
    float* cs     = (float*)alloc((size_t)B_SZ * NHEADS * SEQ * 4);  // 1.05 MB
    unsigned short* statesbf = (unsigned short*)
                    alloc((size_t)B_SZ * NC * NHEADS * HEADDIM * DSTATE * 2);  // 16.78 MB
    unsigned short* Wob = (unsigned short*)alloc((size_t)DOUTSZ * DINNER * 2); // 4.19 MB
    unsigned short* xdT = (unsigned short*)alloc((size_t)B_SZ * NHEADS * 64 * SEQ * 2); // 33.55 MB
    // total ~167 MB

    // aliases (lifetime-disjoint, stream-ordered):
    bf16*  Smat = (bf16*)xbc;                                        // xbc head, after conv
    bf16*  ybuf = (bf16*)((char*)xbc + (size_t)B_SZ * NC * CHUNK * CHUNK * 2);
    unsigned short* BT   = (unsigned short*)ybuf;                    // dead before y_fused writes ybuf
    unsigned short* inpb = (unsigned short*)statesbf;                // dead before chunk_states writes
    unsigned short* Wb   = (unsigned short*)xconv;                   // dead before conv writes xconv

    dim3 blk(256);
    dim3 blk512(512);

    // 0) weight casts to bf16 (one launch): W_in, W_out. (inp cast is fused
    //    into dt_gemm_tiled, which already streams all of inp through LDS.)
    {
        const int n2 = (4384 * DMODEL) / 2048;        // 2192
        const int n3 = (DOUTSZ * DINNER) / 2048;      // 1024
        cast3_f32_bf16<<<dim3(n2 + n3), blk, 0, stream>>>(
            W_in, Wb, n2, W_out, Wob, n3, W_out, Wob);
    }

    // 0.5) dt fp32 GEMM + fused inp -> bf16 cast (writes dtraw AND inpb)
    dt_gemm_tiled<<<dim3(MR / 32), blk, 0, stream>>>(
        inp, W_in + (size_t)(DSSM + CONVDIM) * DMODEL, dtraw, inpb);

    // 1) in_proj: merged z+xBC (N=4352) 256^2-tile 2-phase MFMA
    gemm256_nt<true, unsigned short><<<dim3((DSSM + CONVDIM) / 256, MR / 256), blk512, 0, stream>>>(
        (const short*)inpb, (const short*)Wb,
        (unsigned short*)zb, (unsigned short*)xbc, MR, DSSM + CONVDIM, DMODEL);

    // 2) conv + silu + split (vectorized; xbc dead afterwards)
    conv_silu_v2<<<dim3(CONVDIM / 256, MR / 8), blk, 0, stream>>>(
        (const unsigned short*)xbc, conv_w, conv_b,
        (unsigned short*)xconv, (unsigned short*)Bc, (unsigned short*)Cc);

    // 3) softplus + cumsum fused
    cumsum_da<<<dim3(B_SZ * NHEADS * NC), blk, 0, stream>>>(dtraw, dt_bias, A_log, dtp, cs);

    // 4) S = Cm @ Bm^T per (b,chunk) -> Smat (128^2 coalesced pipelined, batched)
    gemm_mfma_nt<unsigned short><<<dim3(CHUNK / 128, CHUNK / 128, B_SZ * NC), blk512, 0, stream>>>(
        (const short*)Cc, (const short*)Bc, (unsigned short*)Smat, CHUNK, CHUNK, DSTATE,
        (long long)CHUNK * DSTATE, (long long)CHUNK * DSTATE, (long long)CHUNK * CHUNK);

    // 5) xdT precompute (x * dtp, transposed)
    xdt_prep<<<dim3(SEQ / 128, NHEADS, B_SZ), blk, 0, stream>>>(
        (const unsigned short*)xconv, dtp, xdT);

    // 6) BT precompute (B transposed; aliases ybuf head, dead before step 9)
    bt_prep<<<dim3(SEQ / 128, B_SZ), blk, 0, stream>>>((const unsigned short*)Bc, BT);

    // 7) per-chunk states (MFMA, bf16 out; overwrites inpb region)
    chunk_states_mfma<<<dim3(B_SZ * NC * NHEADS), blk, 0, stream>>>(BT, xdT, cs, statesbf);

    // 8) inter-chunk scan (bf16 in place -> prev)
    chunk_scan<<<dim3(B_SZ * NHEADS * HEADDIM * DSTATE / 256), blk, 0, stream>>>(statesbf, cs);

    // 9) fused Y: Y_diag + Y_off + D*x -> ybuf (row-split, grid x2)
    y_fused<<<dim3(B_SZ * NC * NHEADS, 2), blk, 0, stream>>>(
        (const unsigned short*)Smat, (const unsigned short*)Cc, xdT, statesbf,
        cs, Dv, (const unsigned short*)xconv, (unsigned short*)ybuf);

    // 10) gated RMSNorm (in place on ybuf)
    gated_rmsnorm<<<dim3(MR), blk, 0, stream>>>(ybuf, zb, norm_w);

    // 11) out GEMM: 128^2 coalesced pipelined (512 blocks -> all CUs active)
    gemm_mfma_nt<float><<<dim3(DOUTSZ / 128, MR / 128), blk512, 0, stream>>>(
        (const short*)ybuf, (const short*)Wob, out, MR, DOUTSZ, DINNER, 0, 0, 0);
}